// Round 3
// baseline (283.444 us; speedup 1.0000x reference)
//
#include <hip/hip_runtime.h>

#define B_ 4
#define S_ 2048
#define D_ 512
#define H_ 8

typedef __attribute__((ext_vector_type(8))) __bf16 bf16x8;
typedef __attribute__((ext_vector_type(4))) float f32x4;

#define NEGBIG  -1.442695040e9f          // -1e9 * log2(e): masks live in exp2 domain
#define QSCALE  0.18033688011112042f     // 0.125 * log2(e) folded into Q

// pack two floats -> two bf16 (RNE-ish, ties-up): 2 adds + 1 v_perm
__device__ __forceinline__ unsigned pack_rn(float a, float b) {
    union { float f; unsigned u; } ua, ub; ua.f = a; ub.f = b;
    return __builtin_amdgcn_perm(ub.u + 0x8000u, ua.u + 0x8000u, 0x07060302u);
}

// ---------------------------------------------------------------------------
// fp32 -> bf16 cast of activations (row-major unchanged).
// ---------------------------------------------------------------------------
__global__ __launch_bounds__(256) void cast_x(
    const float* __restrict__ q, const float* __restrict__ v,
    unsigned short* __restrict__ xq, unsigned short* __restrict__ xv)
{
    const float* src = blockIdx.z ? v : q;
    unsigned short* dst = blockIdx.z ? xv : xq;
    int i = (blockIdx.x * 256 + threadIdx.x) * 8;
    float4 f0 = *(const float4*)&src[i];
    float4 f1 = *(const float4*)&src[i + 4];
    uint4 o;
    o.x = pack_rn(f0.x, f0.y); o.y = pack_rn(f0.z, f0.w);
    o.z = pack_rn(f1.x, f1.y); o.w = pack_rn(f1.z, f1.w);
    *(uint4*)&dst[i] = o;
}

// ---------------------------------------------------------------------------
// int attention mask -> fp32 additive mask in exp2 domain (0 or -1e9*log2e).
// ---------------------------------------------------------------------------
__global__ __launch_bounds__(256) void mask_f(
    const int* __restrict__ am, float* __restrict__ Mf)
{
    int i = (blockIdx.x * 256 + threadIdx.x) * 4;
    int4 m = *(const int4*)&am[i];
    float4 o;
    o.x = m.x ? 0.f : NEGBIG;
    o.y = m.y ? 0.f : NEGBIG;
    o.z = m.z ? 0.f : NEGBIG;
    o.w = m.w ? 0.f : NEGBIG;
    *(float4*)&Mf[i] = o;
}

// ---------------------------------------------------------------------------
// Coalesced weight cast+transpose: Wt[n][k] = bf16(W[k][n]), via LDS tile.
// ---------------------------------------------------------------------------
__global__ __launch_bounds__(256) void cast_wt(
    const float* __restrict__ Wq, const float* __restrict__ Wk,
    const float* __restrict__ Wv, const float* __restrict__ Wo,
    unsigned short* __restrict__ Tq, unsigned short* __restrict__ Tk,
    unsigned short* __restrict__ Tv, unsigned short* __restrict__ To)
{
    int z = blockIdx.z;
    const float* W = (z == 0) ? Wq : (z == 1) ? Wk : (z == 2) ? Wv : Wo;
    unsigned short* T = (z == 0) ? Tq : (z == 1) ? Tk : (z == 2) ? Tv : To;
    int n0 = blockIdx.x * 64, k0 = blockIdx.y * 64;
    int tid = threadIdx.x;

    __shared__ float Ts[64][69];
    #pragma unroll
    for (int it = 0; it < 4; it++) {
        int lin = tid + it * 256;
        int kr = lin >> 4, c4 = (lin & 15) * 4;
        float4 v = *(const float4*)&W[(k0 + kr) * 512 + n0 + c4];
        Ts[kr][c4 + 0] = v.x; Ts[kr][c4 + 1] = v.y;
        Ts[kr][c4 + 2] = v.z; Ts[kr][c4 + 3] = v.w;
    }
    __syncthreads();
    int n = tid >> 2, kc = tid & 3;
    unsigned p[8];
    #pragma unroll
    for (int j = 0; j < 8; j++)
        p[j] = pack_rn(Ts[kc * 16 + 2 * j][n], Ts[kc * 16 + 2 * j + 1][n]);
    unsigned short* dst = &T[(n0 + n) * 512 + k0 + kc * 16];
    *(uint4*)dst       = *(uint4*)&p[0];
    *(uint4*)(dst + 8) = *(uint4*)&p[4];
}

// ---------------------------------------------------------------------------
// QKV projection GEMM, all-bf16 staging, 128x128 tile, 4 waves (2x2 of 64).
// ---------------------------------------------------------------------------
__global__ __launch_bounds__(256) void proj_qkv_mfma(
    const unsigned short* __restrict__ Xq, const unsigned short* __restrict__ Xv,
    const unsigned short* __restrict__ Wtq, const unsigned short* __restrict__ Wtk,
    const unsigned short* __restrict__ Wtv,
    const float* __restrict__ bq, const float* __restrict__ bk,
    const float* __restrict__ bv,
    unsigned short* __restrict__ Qb, unsigned short* __restrict__ Kb,
    unsigned short* __restrict__ VtG)
{
    const int z = blockIdx.z;
    const unsigned short* A  = (z == 0) ? Wtq : (z == 1) ? Wtk : Xv;
    const unsigned short* Bm = (z == 0) ? Xq  : (z == 1) ? Xv  : Wtv;
    const float* bias        = (z == 0) ? bq  : (z == 1) ? bk  : bv;
    const int m0 = (z < 2) ? blockIdx.y * 128 : blockIdx.x * 128;
    const int n0 = (z < 2) ? blockIdx.x * 128 : blockIdx.y * 128;

    const int tid = threadIdx.x;
    const int w = tid >> 6, lane = tid & 63;
    const int l15 = lane & 15, quad = lane >> 4;
    const int wm = (w >> 1) * 64, wn = (w & 1) * 64;

    __shared__ unsigned short As[128 * 72];
    __shared__ unsigned short Bs[128 * 72];

    f32x4 acc[4][4];
    #pragma unroll
    for (int i = 0; i < 4; i++)
        #pragma unroll
        for (int j = 0; j < 4; j++) acc[i][j] = (f32x4){0.f, 0.f, 0.f, 0.f};

    for (int k0 = 0; k0 < 512; k0 += 64) {
        __syncthreads();
        #pragma unroll
        for (int it = 0; it < 2; it++) {
            int lin = tid + it * 256;
            int row = lin >> 2, c2 = (lin & 3) * 2;   // 2 of 8 chunks per row
            *(uint4*)&As[row * 72 + c2 * 8]     = *(const uint4*)&A[(m0 + row) * 512 + k0 + c2 * 8];
            *(uint4*)&As[row * 72 + c2 * 8 + 8] = *(const uint4*)&A[(m0 + row) * 512 + k0 + c2 * 8 + 8];
            *(uint4*)&Bs[row * 72 + c2 * 8]     = *(const uint4*)&Bm[(n0 + row) * 512 + k0 + c2 * 8];
            *(uint4*)&Bs[row * 72 + c2 * 8 + 8] = *(const uint4*)&Bm[(n0 + row) * 512 + k0 + c2 * 8 + 8];
        }
        __syncthreads();
        #pragma unroll
        for (int kc = 0; kc < 2; kc++) {
            bf16x8 a[4], bb[4];
            #pragma unroll
            for (int i = 0; i < 4; i++)
                a[i] = *(const bf16x8*)&As[(wm + 16 * i + l15) * 72 + kc * 32 + quad * 8];
            #pragma unroll
            for (int j = 0; j < 4; j++)
                bb[j] = *(const bf16x8*)&Bs[(wn + 16 * j + l15) * 72 + kc * 32 + quad * 8];
            #pragma unroll
            for (int i = 0; i < 4; i++)
                #pragma unroll
                for (int j = 0; j < 4; j++)
                    acc[i][j] = __builtin_amdgcn_mfma_f32_16x16x32_bf16(a[i], bb[j], acc[i][j], 0, 0, 0);
        }
    }

    if (z == 2) {
        #pragma unroll
        for (int j = 0; j < 4; j++) {
            int N = n0 + wn + 16 * j + l15;
            float bv_ = bias[N];
            int h = N >> 6, d = N & 63;
            #pragma unroll
            for (int i = 0; i < 4; i++) {
                int Mb = m0 + wm + 16 * i + quad * 4;
                int b = Mb >> 11, s = Mb & 2047;
                uint2 o;
                o.x = pack_rn(acc[i][j][0] + bv_, acc[i][j][1] + bv_);
                o.y = pack_rn(acc[i][j][2] + bv_, acc[i][j][3] + bv_);
                *(uint2*)&VtG[((b * H_ + h) * 64 + d) * 2048 + s] = o;
            }
        }
    } else {
        unsigned short* dst = (z == 0) ? Qb : Kb;
        const float scale = (z == 0) ? QSCALE : 1.0f;
        #pragma unroll
        for (int j = 0; j < 4; j++) {
            int sg = n0 + wn + 16 * j + l15;
            int b = sg >> 11, s = sg & 2047;
            #pragma unroll
            for (int i = 0; i < 4; i++) {
                int F = m0 + wm + 16 * i + quad * 4;
                int h = F >> 6, d = F & 63;
                float4 b4 = *(const float4*)&bias[F];
                uint2 o;
                o.x = pack_rn((acc[i][j][0] + b4.x) * scale, (acc[i][j][1] + b4.y) * scale);
                o.y = pack_rn((acc[i][j][2] + b4.z) * scale, (acc[i][j][3] + b4.w) * scale);
                *(uint2*)&dst[((b * H_ + h) * 2048 + s) * 64 + d] = o;
            }
        }
    }
}

// ---------------------------------------------------------------------------
// MFMA flash attention. 512-thread blocks = 8 waves x 16 q-rows (128-q tile).
// Same proven pipeline as the 214us baseline (cooperative LDS K-staging,
// ONE barrier per 64-key tile: load t+1 -> compute t -> ds_write t+1 ->
// barrier; V direct-global issued early), but:
//   - 8 waves/block => 16 waves/CU = 4 waves/SIMD (was 2): grid was the
//     occupancy cap (VGPR 112 / LDS 38KB never were). Per-wave state halves
//     so VGPR stays <=128 (enforced by __launch_bounds__(512,4)).
//   - XCD-aware swizzle: XCD x owns bh in {4x..4x+3} => K/V working set
//     2 MB/XCD stays L2-resident; staging loads become L2 hits.
//   - masks precomputed fp32 in exp2 domain, folded into MFMA C-init (exact).
//   - defer-max (THR=4): skip O/li rescale while running max holds.
//   - s_setprio(1) around MFMA clusters.
// ---------------------------------------------------------------------------
__global__ __launch_bounds__(512, 4) void flash_mfma(
    const unsigned short* __restrict__ Qg, const unsigned short* __restrict__ Kg,
    const unsigned short* __restrict__ VtG, const float* __restrict__ Mf,
    unsigned short* __restrict__ ctxB)
{
    // XCD swizzle (blocks round-robin XCDs by linear id): bid -> (bh, qtile)
    const int bid = blockIdx.x;                  // 0..511
    const int xcd = bid & 7, idx = bid >> 3;     // idx 0..63
    const int bh = xcd * 4 + (idx & 3);          // XCD x: bh 4x..4x+3
    const int q0 = (idx >> 2) * 128;             // 16 q-tiles
    const int b = bh >> 3, h = bh & 7;

    const int tid = threadIdx.x;
    const int w = tid >> 6, lane = tid & 63;
    const int l15 = lane & 15, quad = lane >> 4;

    __shared__ unsigned short Ks[2][64 * 72];    // double-buffered K tile [key][d]
    __shared__ unsigned short Ps[8][16 * 72];    // per-wave P region [q][key]
    unsigned short* pw = &Ps[w][0];

    const float* mfb = Mf + b * 2048;
    const float* mp = mfb + quad * 4;

    // Q fragment (B-operand) + query mask: wave w owns q rows q0+w*16+l15
    const int qrow = q0 + w * 16 + l15;
    bf16x8 qf0, qf1;
    {
        const unsigned short* p = &Qg[((long)bh * 2048 + qrow) * 64 + quad * 8];
        qf0 = *(const bf16x8*)p;
        qf1 = *(const bf16x8*)(p + 32);
    }
    const float mq = mfb[qrow];

    // V row pointers (bh,d,s layout)
    const unsigned short* vp[4];
    #pragma unroll
    for (int i = 0; i < 4; i++)
        vp[i] = VtG + ((long)bh * 64 + i * 16 + l15) * 2048 + quad * 8;

    // K staging: 512 threads x one uint4 = 64x64 bf16 tile
    const int srow = tid >> 3;          // 0..63
    const int sch  = tid & 7;           // 8-short chunk
    const unsigned short* kgb = Kg + (long)bh * 2048 * 64;

    // preamble: stage tile 0
    *(uint4*)&Ks[0][srow * 72 + sch * 8] = *(const uint4*)&kgb[srow * 64 + sch * 8];

    f32x4 accO[4];
    #pragma unroll
    for (int dt = 0; dt < 4; dt++) accO[dt] = (f32x4){0.f, 0.f, 0.f, 0.f};
    float mi = -3.0e38f;
    float li = 0.f;

    __syncthreads();

    for (int t = 0; t < 32; t++) {
        const int kt = t * 64;
        const int ktn = (t < 31) ? kt + 64 : kt;
        const int cur = t & 1, nxt = cur ^ 1;

        // [A] issue global loads: V frags + key-masks for THIS tile, K for NEXT
        bf16x8 vf[4][2];
        #pragma unroll
        for (int dt = 0; dt < 4; dt++) {
            vf[dt][0] = *(const bf16x8*)(vp[dt] + kt);
            vf[dt][1] = *(const bf16x8*)(vp[dt] + kt + 32);
        }
        uint4 kst = *(const uint4*)&kgb[(ktn + srow) * 64 + sch * 8];
        f32x4 kmf[4];
        #pragma unroll
        for (int nt = 0; nt < 4; nt++)
            kmf[nt] = *(const f32x4*)(mp + kt + nt * 16);

        // [C] K frags from LDS buf[cur]; QK: S^T (rows=key, cols=q)
        bf16x8 kf[4][2];
        #pragma unroll
        for (int nt = 0; nt < 4; nt++)
            #pragma unroll
            for (int kc = 0; kc < 2; kc++)
                kf[nt][kc] = *(const bf16x8*)&Ks[cur][(nt * 16 + l15) * 72 + kc * 32 + quad * 8];

        f32x4 sc[4];
        #pragma unroll
        for (int nt = 0; nt < 4; nt++) {
            f32x4 c = kmf[nt];                   // masks as C-init: exact
            c[0] += mq; c[1] += mq; c[2] += mq; c[3] += mq;
            sc[nt] = c;
        }
        __builtin_amdgcn_s_setprio(1);
        #pragma unroll
        for (int nt = 0; nt < 4; nt++) {
            sc[nt] = __builtin_amdgcn_mfma_f32_16x16x32_bf16(kf[nt][0], qf0, sc[nt], 0, 0, 0);
            sc[nt] = __builtin_amdgcn_mfma_f32_16x16x32_bf16(kf[nt][1], qf1, sc[nt], 0, 0, 0);
        }
        __builtin_amdgcn_s_setprio(0);

        // [D] online softmax (reduce over keys = in-lane + quad shfls)
        {
            float mloc = fmaxf(fmaxf(sc[0][0], sc[0][1]), fmaxf(sc[0][2], sc[0][3]));
            #pragma unroll
            for (int nt = 1; nt < 4; nt++)
                mloc = fmaxf(mloc, fmaxf(fmaxf(sc[nt][0], sc[nt][1]),
                                         fmaxf(sc[nt][2], sc[nt][3])));
            mloc = fmaxf(mloc, __shfl_xor(mloc, 16));
            mloc = fmaxf(mloc, __shfl_xor(mloc, 32));

            float mn = mi;
            if (!__all(mloc <= mn + 4.f)) {      // defer-max: P bounded by 2^4
                float mo = mn;
                mn = fmaxf(mo, mloc);
                float alpha = __builtin_amdgcn_exp2f(mo - mn);
                li *= alpha;
                #pragma unroll
                for (int dt = 0; dt < 4; dt++) {
                    accO[dt][0] *= alpha; accO[dt][1] *= alpha;
                    accO[dt][2] *= alpha; accO[dt][3] *= alpha;
                }
                mi = mn;
            }

            float ps = 0.f;
            #pragma unroll
            for (int nt = 0; nt < 4; nt++) {
                float p0 = __builtin_amdgcn_exp2f(sc[nt][0] - mn);
                float p1 = __builtin_amdgcn_exp2f(sc[nt][1] - mn);
                float p2 = __builtin_amdgcn_exp2f(sc[nt][2] - mn);
                float p3 = __builtin_amdgcn_exp2f(sc[nt][3] - mn);
                ps += (p0 + p1) + (p2 + p3);
                int prow = l15 * 72 + nt * 16 + quad * 4;
                *(unsigned*)&pw[prow]     = pack_rn(p0, p1);
                *(unsigned*)&pw[prow + 2] = pack_rn(p2, p3);
            }
            ps += __shfl_xor(ps, 16);
            ps += __shfl_xor(ps, 32);
            li += ps;
        }

        // [E] PV: O^T += Vt (A) x P^T (B)
        {
            bf16x8 pf0 = *(const bf16x8*)&pw[l15 * 72 + quad * 8];
            bf16x8 pf1 = *(const bf16x8*)&pw[l15 * 72 + 32 + quad * 8];
            __builtin_amdgcn_s_setprio(1);
            #pragma unroll
            for (int dt = 0; dt < 4; dt++) {
                accO[dt] = __builtin_amdgcn_mfma_f32_16x16x32_bf16(
                    vf[dt][0], pf0, accO[dt], 0, 0, 0);
                accO[dt] = __builtin_amdgcn_mfma_f32_16x16x32_bf16(
                    vf[dt][1], pf1, accO[dt], 0, 0, 0);
            }
            __builtin_amdgcn_s_setprio(0);
        }

        // [F] commit next K tile (waits the [A] load), [G] barrier
        *(uint4*)&Ks[nxt][srow * 72 + sch * 8] = kst;
        __syncthreads();
    }

    {
        float inv = 1.f / li;
        int obase = (b * 2048 + qrow) * 512 + h * 64 + quad * 4;
        #pragma unroll
        for (int dt = 0; dt < 4; dt++) {
            uint2 o;
            o.x = pack_rn(accO[dt][0] * inv, accO[dt][1] * inv);
            o.y = pack_rn(accO[dt][2] * inv, accO[dt][3] * inv);
            *(uint2*)&ctxB[obase + dt * 16] = o;
        }
    }
}

// ---------------------------------------------------------------------------
// Output projection: out(fp32) = ctx_bf16 @ Wo + bo.
// ---------------------------------------------------------------------------
__global__ __launch_bounds__(256) void proj_out_mfma(
    const unsigned short* __restrict__ ctxB, const unsigned short* __restrict__ Wto,
    const float* __restrict__ bo, float* __restrict__ out)
{
    const int m0 = blockIdx.y * 128, n0 = blockIdx.x * 128;
    const int tid = threadIdx.x;
    const int w = tid >> 6, lane = tid & 63;
    const int l15 = lane & 15, quad = lane >> 4;
    const int wm = (w >> 1) * 64, wn = (w & 1) * 64;

    __shared__ unsigned short As[128 * 72];
    __shared__ unsigned short Bs[128 * 72];

    f32x4 acc[4][4];
    #pragma unroll
    for (int i = 0; i < 4; i++)
        #pragma unroll
        for (int j = 0; j < 4; j++) acc[i][j] = (f32x4){0.f, 0.f, 0.f, 0.f};

    for (int k0 = 0; k0 < 512; k0 += 64) {
        __syncthreads();
        #pragma unroll
        for (int it = 0; it < 2; it++) {
            int lin = tid + it * 256;
            int row = lin >> 2, c2 = (lin & 3) * 2;
            *(uint4*)&As[row * 72 + c2 * 8]     = *(const uint4*)&Wto[(m0 + row) * 512 + k0 + c2 * 8];
            *(uint4*)&As[row * 72 + c2 * 8 + 8] = *(const uint4*)&Wto[(m0 + row) * 512 + k0 + c2 * 8 + 8];
            *(uint4*)&Bs[row * 72 + c2 * 8]     = *(const uint4*)&ctxB[(n0 + row) * 512 + k0 + c2 * 8];
            *(uint4*)&Bs[row * 72 + c2 * 8 + 8] = *(const uint4*)&ctxB[(n0 + row) * 512 + k0 + c2 * 8 + 8];
        }
        __syncthreads();
        #pragma unroll
        for (int kc = 0; kc < 2; kc++) {
            bf16x8 a[4], bb[4];
            #pragma unroll
            for (int i = 0; i < 4; i++)
                a[i] = *(const bf16x8*)&As[(wm + 16 * i + l15) * 72 + kc * 32 + quad * 8];
            #pragma unroll
            for (int j = 0; j < 4; j++)
                bb[j] = *(const bf16x8*)&Bs[(wn + 16 * j + l15) * 72 + kc * 32 + quad * 8];
            #pragma unroll
            for (int i = 0; i < 4; i++)
                #pragma unroll
                for (int j = 0; j < 4; j++)
                    acc[i][j] = __builtin_amdgcn_mfma_f32_16x16x32_bf16(a[i], bb[j], acc[i][j], 0, 0, 0);
        }
    }

    #pragma unroll
    for (int j = 0; j < 4; j++) {
        int sg = n0 + wn + 16 * j + l15;
        #pragma unroll
        for (int i = 0; i < 4; i++) {
            int F = m0 + wm + 16 * i + quad * 4;
            float4 b4 = *(const float4*)&bo[F];
            float4 vv;
            vv.x = acc[i][j][0] + b4.x;
            vv.y = acc[i][j][1] + b4.y;
            vv.z = acc[i][j][2] + b4.z;
            vv.w = acc[i][j][3] + b4.w;
            *(float4*)&out[sg * 512 + F] = vv;
        }
    }
}

extern "C" void kernel_launch(void* const* d_in, const int* in_sizes, int n_in,
                              void* d_out, int out_size, void* d_ws, size_t ws_size,
                              hipStream_t stream)
{
    const float* query = (const float*)d_in[0];
    const float* value = (const float*)d_in[1];
    const int*   amask = (const int*)d_in[2];
    const float* Wq = (const float*)d_in[3];
    const float* bq = (const float*)d_in[4];
    const float* Wk = (const float*)d_in[5];
    const float* bk = (const float*)d_in[6];
    const float* Wv = (const float*)d_in[7];
    const float* bv = (const float*)d_in[8];
    const float* Wo = (const float*)d_in[9];
    const float* bo = (const float*)d_in[10];
    float* out = (float*)d_out;

    char* ws = (char*)d_ws;
    const size_t MB = 1 << 20;
    unsigned short* Xbq = (unsigned short*)(ws);                  // 8 MB bf16
    unsigned short* Xbv = (unsigned short*)(ws + 8 * MB);         // 8 MB
    unsigned short* Wtq = (unsigned short*)(ws + 16 * MB);        // 0.5 MB each
    unsigned short* Wtk = (unsigned short*)(ws + 16 * MB + MB / 2);
    unsigned short* Wtv = (unsigned short*)(ws + 17 * MB);
    unsigned short* Wto = (unsigned short*)(ws + 17 * MB + MB / 2);
    unsigned short* Qb  = (unsigned short*)(ws + 18 * MB);        // 8 MB (bh,s,d)
    unsigned short* Kb  = (unsigned short*)(ws + 26 * MB);        // 8 MB (bh,s,d)
    unsigned short* VtG = (unsigned short*)(ws + 34 * MB);        // 8 MB (bh,d,s)
    unsigned short* ctx = (unsigned short*)(ws + 42 * MB);        // 8 MB (b*s, h*d)
    float* Mf = (float*)(ws);   // 32 KB fp32 mask — reuses Xbq region, which is
                                // dead after proj_qkv_mfma (stream-ordered)

    cast_x<<<dim3(2048, 1, 2), 256, 0, stream>>>(query, value, Xbq, Xbv);
    cast_wt<<<dim3(8, 8, 4), 256, 0, stream>>>(Wq, Wk, Wv, Wo, Wtq, Wtk, Wtv, Wto);
    proj_qkv_mfma<<<dim3(64, 4, 3), 256, 0, stream>>>(Xbq, Xbv, Wtq, Wtk, Wtv,
                                                      bq, bk, bv, Qb, Kb, VtG);
    mask_f<<<dim3(8), 256, 0, stream>>>(amask, Mf);
    flash_mfma<<<dim3(512), 512, 0, stream>>>(Qb, Kb, VtG, Mf, ctx);
    proj_out_mfma<<<dim3(64, 4), 256, 0, stream>>>(ctx, Wto, bo, out);
}

// Round 4
// 212.619 us; speedup vs baseline: 1.3331x; 1.3331x over previous
//
#include <hip/hip_runtime.h>

#define B_ 4
#define S_ 2048
#define D_ 512
#define H_ 8

typedef __attribute__((ext_vector_type(8))) __bf16 bf16x8;
typedef __attribute__((ext_vector_type(4))) float f32x4;

#define NEGBIG  -1.442695040e9f          // -1e9 * log2(e): masks live in exp2 domain
#define QSCALE  0.18033688011112042f     // 0.125 * log2(e) folded into Q

// pack two floats -> two bf16 (RNE-ish, ties-up): 2 adds + 1 v_perm
__device__ __forceinline__ unsigned pack_rn(float a, float b) {
    union { float f; unsigned u; } ua, ub; ua.f = a; ub.f = b;
    return __builtin_amdgcn_perm(ub.u + 0x8000u, ua.u + 0x8000u, 0x07060302u);
}

// ---------------------------------------------------------------------------
// fp32 -> bf16 cast of activations (row-major unchanged).
// ---------------------------------------------------------------------------
__global__ __launch_bounds__(256) void cast_x(
    const float* __restrict__ q, const float* __restrict__ v,
    unsigned short* __restrict__ xq, unsigned short* __restrict__ xv)
{
    const float* src = blockIdx.z ? v : q;
    unsigned short* dst = blockIdx.z ? xv : xq;
    int i = (blockIdx.x * 256 + threadIdx.x) * 8;
    float4 f0 = *(const float4*)&src[i];
    float4 f1 = *(const float4*)&src[i + 4];
    uint4 o;
    o.x = pack_rn(f0.x, f0.y); o.y = pack_rn(f0.z, f0.w);
    o.z = pack_rn(f1.x, f1.y); o.w = pack_rn(f1.z, f1.w);
    *(uint4*)&dst[i] = o;
}

// ---------------------------------------------------------------------------
// Per-batch key compaction: idx[b][i] = i-th valid key position, nv1[b] = count.
// One wave per batch, ballot-scan over 32 chunks of 64.
// ---------------------------------------------------------------------------
__global__ __launch_bounds__(256) void compact_k(
    const int* __restrict__ am, int* __restrict__ idxc, int* __restrict__ nv1)
{
    const int w = threadIdx.x >> 6;          // batch
    const int lane = threadIdx.x & 63;
    const int* amb = am + w * 2048;
    int* ib = idxc + w * 2048;
    const unsigned long long ltmask = (1ULL << lane) - 1ULL;
    int base = 0;
    for (int step = 0; step < 32; ++step) {
        int s = step * 64 + lane;
        int m = amb[s];
        unsigned long long bal = __ballot(m != 0);
        if (m) ib[base + __popcll(bal & ltmask)] = s;
        base += __popcll(bal);
    }
    if (lane == 0) nv1[w] = base;
}

// ---------------------------------------------------------------------------
// Post-proj mask materialization (runs AFTER proj_qkv so it may reuse the then-
// dead Xbq region): Mf = query mask (original order, exp2 domain);
// Mc = compacted key mask (0 for i<nv, NEGBIG pad); nv2 = copy of nv1.
// ---------------------------------------------------------------------------
__global__ __launch_bounds__(256) void mask_fc(
    const int* __restrict__ am, const int* __restrict__ nv1,
    float* __restrict__ Mf, float* __restrict__ Mc, int* __restrict__ nv2)
{
    int g = (blockIdx.x * 256 + threadIdx.x) * 4;
    int b = g >> 11, loc = g & 2047;
    int nv = nv1[b];
    int4 m = *(const int4*)&am[g];
    float4 o, c;
    o.x = m.x ? 0.f : NEGBIG;
    o.y = m.y ? 0.f : NEGBIG;
    o.z = m.z ? 0.f : NEGBIG;
    o.w = m.w ? 0.f : NEGBIG;
    c.x = (loc + 0 < nv) ? 0.f : NEGBIG;
    c.y = (loc + 1 < nv) ? 0.f : NEGBIG;
    c.z = (loc + 2 < nv) ? 0.f : NEGBIG;
    c.w = (loc + 3 < nv) ? 0.f : NEGBIG;
    *(float4*)&Mf[g] = o;
    *(float4*)&Mc[g] = c;
    if (blockIdx.x == 0 && threadIdx.x < 4) nv2[threadIdx.x] = nv1[threadIdx.x];
}

// ---------------------------------------------------------------------------
// Coalesced weight cast+transpose: Wt[n][k] = bf16(W[k][n]), via LDS tile.
// ---------------------------------------------------------------------------
__global__ __launch_bounds__(256) void cast_wt(
    const float* __restrict__ Wq, const float* __restrict__ Wk,
    const float* __restrict__ Wv, const float* __restrict__ Wo,
    unsigned short* __restrict__ Tq, unsigned short* __restrict__ Tk,
    unsigned short* __restrict__ Tv, unsigned short* __restrict__ To)
{
    int z = blockIdx.z;
    const float* W = (z == 0) ? Wq : (z == 1) ? Wk : (z == 2) ? Wv : Wo;
    unsigned short* T = (z == 0) ? Tq : (z == 1) ? Tk : (z == 2) ? Tv : To;
    int n0 = blockIdx.x * 64, k0 = blockIdx.y * 64;
    int tid = threadIdx.x;

    __shared__ float Ts[64][69];
    #pragma unroll
    for (int it = 0; it < 4; it++) {
        int lin = tid + it * 256;
        int kr = lin >> 4, c4 = (lin & 15) * 4;
        float4 v = *(const float4*)&W[(k0 + kr) * 512 + n0 + c4];
        Ts[kr][c4 + 0] = v.x; Ts[kr][c4 + 1] = v.y;
        Ts[kr][c4 + 2] = v.z; Ts[kr][c4 + 3] = v.w;
    }
    __syncthreads();
    int n = tid >> 2, kc = tid & 3;
    unsigned p[8];
    #pragma unroll
    for (int j = 0; j < 8; j++)
        p[j] = pack_rn(Ts[kc * 16 + 2 * j][n], Ts[kc * 16 + 2 * j + 1][n]);
    unsigned short* dst = &T[(n0 + n) * 512 + k0 + kc * 16];
    *(uint4*)dst       = *(uint4*)&p[0];
    *(uint4*)(dst + 8) = *(uint4*)&p[4];
}

// ---------------------------------------------------------------------------
// QKV projection GEMM with fused key-compaction gather.
// z=0 (Q): A=Wtq (m=feature), B=Xq (n=s, full) -> (bh,s,d), scaled.
// z=1 (K): A=Wtk (m=feature), B=Xv GATHERED by idx (n=compacted s) -> (bh,i,d).
// z=2 (V): A=Xv GATHERED (m=compacted s), B=Wtv (n=feature) -> (bh,d,i).
// Blocks whose compacted-row range >= roundup128(nv) exit early. Gathered rows
// beyond nv are zero-filled (K/V = bias there; masked out by Mc in flash).
// ---------------------------------------------------------------------------
__global__ __launch_bounds__(256) void proj_qkv_mfma(
    const unsigned short* __restrict__ Xq, const unsigned short* __restrict__ Xv,
    const unsigned short* __restrict__ Wtq, const unsigned short* __restrict__ Wtk,
    const unsigned short* __restrict__ Wtv,
    const float* __restrict__ bq, const float* __restrict__ bk,
    const float* __restrict__ bv,
    const int* __restrict__ idxc, const int* __restrict__ nv1,
    unsigned short* __restrict__ Qb, unsigned short* __restrict__ Kb,
    unsigned short* __restrict__ VtG)
{
    const int z = blockIdx.z;
    const unsigned short* A  = (z == 0) ? Wtq : (z == 1) ? Wtk : Xv;
    const unsigned short* Bm = (z == 0) ? Xq  : (z == 1) ? Xv  : Wtv;
    const float* bias        = (z == 0) ? bq  : (z == 1) ? bk  : bv;
    const int m0 = (z < 2) ? blockIdx.y * 128 : blockIdx.x * 128;
    const int n0 = (z < 2) ? blockIdx.x * 128 : blockIdx.y * 128;

    // early-exit for blocks entirely in the dead compacted region
    if (z == 1) {
        int bb = n0 >> 11, cap = (nv1[bb] + 127) & ~127;
        if (cap < 128) cap = 128;
        if ((n0 & 2047) >= cap) return;
    }
    if (z == 2) {
        int bb = m0 >> 11, cap = (nv1[bb] + 127) & ~127;
        if (cap < 128) cap = 128;
        if ((m0 & 2047) >= cap) return;
    }

    const int tid = threadIdx.x;
    const int w = tid >> 6, lane = tid & 63;
    const int l15 = lane & 15, quad = lane >> 4;
    const int wm = (w >> 1) * 64, wn = (w & 1) * 64;

    __shared__ unsigned short As[128 * 72];
    __shared__ unsigned short Bs[128 * 72];

    // precompute gathered source offsets for the two staged rows per thread
    long aoff[2], boff[2];
    bool az[2] = {false, false}, bz[2] = {false, false};
    #pragma unroll
    for (int it = 0; it < 2; it++) {
        int row = (tid + it * 256) >> 2;
        long sa = m0 + row, sb = n0 + row;
        if (z == 2) {
            int bb = (m0 + row) >> 11, loc = (m0 + row) & 2047;
            if (loc < nv1[bb]) sa = bb * 2048 + idxc[bb * 2048 + loc];
            else az[it] = true;
        }
        if (z == 1) {
            int bb = (n0 + row) >> 11, loc = (n0 + row) & 2047;
            if (loc < nv1[bb]) sb = bb * 2048 + idxc[bb * 2048 + loc];
            else bz[it] = true;
        }
        aoff[it] = sa * 512; boff[it] = sb * 512;
    }

    f32x4 acc[4][4];
    #pragma unroll
    for (int i = 0; i < 4; i++)
        #pragma unroll
        for (int j = 0; j < 4; j++) acc[i][j] = (f32x4){0.f, 0.f, 0.f, 0.f};

    const uint4 zero4 = {0u, 0u, 0u, 0u};
    for (int k0 = 0; k0 < 512; k0 += 64) {
        __syncthreads();
        #pragma unroll
        for (int it = 0; it < 2; it++) {
            int lin = tid + it * 256;
            int row = lin >> 2, c2 = (lin & 3) * 2;   // 2 of 8 chunks per row
            uint4 a0 = az[it] ? zero4 : *(const uint4*)&A[aoff[it] + k0 + c2 * 8];
            uint4 a1 = az[it] ? zero4 : *(const uint4*)&A[aoff[it] + k0 + c2 * 8 + 8];
            uint4 b0 = bz[it] ? zero4 : *(const uint4*)&Bm[boff[it] + k0 + c2 * 8];
            uint4 b1 = bz[it] ? zero4 : *(const uint4*)&Bm[boff[it] + k0 + c2 * 8 + 8];
            *(uint4*)&As[row * 72 + c2 * 8]     = a0;
            *(uint4*)&As[row * 72 + c2 * 8 + 8] = a1;
            *(uint4*)&Bs[row * 72 + c2 * 8]     = b0;
            *(uint4*)&Bs[row * 72 + c2 * 8 + 8] = b1;
        }
        __syncthreads();
        #pragma unroll
        for (int kc = 0; kc < 2; kc++) {
            bf16x8 a[4], bb[4];
            #pragma unroll
            for (int i = 0; i < 4; i++)
                a[i] = *(const bf16x8*)&As[(wm + 16 * i + l15) * 72 + kc * 32 + quad * 8];
            #pragma unroll
            for (int j = 0; j < 4; j++)
                bb[j] = *(const bf16x8*)&Bs[(wn + 16 * j + l15) * 72 + kc * 32 + quad * 8];
            #pragma unroll
            for (int i = 0; i < 4; i++)
                #pragma unroll
                for (int j = 0; j < 4; j++)
                    acc[i][j] = __builtin_amdgcn_mfma_f32_16x16x32_bf16(a[i], bb[j], acc[i][j], 0, 0, 0);
        }
    }

    if (z == 2) {
        // V: cols = feature, rows = compacted s. ushort4 along s into (bh,d,i).
        #pragma unroll
        for (int j = 0; j < 4; j++) {
            int N = n0 + wn + 16 * j + l15;
            float bv_ = bias[N];
            int h = N >> 6, d = N & 63;
            #pragma unroll
            for (int i = 0; i < 4; i++) {
                int Mb = m0 + wm + 16 * i + quad * 4;
                int b = Mb >> 11, s = Mb & 2047;
                uint2 o;
                o.x = pack_rn(acc[i][j][0] + bv_, acc[i][j][1] + bv_);
                o.y = pack_rn(acc[i][j][2] + bv_, acc[i][j][3] + bv_);
                *(uint2*)&VtG[((b * H_ + h) * 64 + d) * 2048 + s] = o;
            }
        }
    } else {
        // Q/K: cols = s (K: compacted), rows = feature. ushort4 along d.
        unsigned short* dst = (z == 0) ? Qb : Kb;
        const float scale = (z == 0) ? QSCALE : 1.0f;
        #pragma unroll
        for (int j = 0; j < 4; j++) {
            int sg = n0 + wn + 16 * j + l15;
            int b = sg >> 11, s = sg & 2047;
            #pragma unroll
            for (int i = 0; i < 4; i++) {
                int F = m0 + wm + 16 * i + quad * 4;
                int h = F >> 6, d = F & 63;
                float4 b4 = *(const float4*)&bias[F];
                uint2 o;
                o.x = pack_rn((acc[i][j][0] + b4.x) * scale, (acc[i][j][1] + b4.y) * scale);
                o.y = pack_rn((acc[i][j][2] + b4.z) * scale, (acc[i][j][3] + b4.w) * scale);
                *(uint2*)&dst[((b * H_ + h) * 2048 + s) * 64 + d] = o;
            }
        }
    }
}

// ---------------------------------------------------------------------------
// MFMA flash attention over COMPACTED keys (~half the tiles; dropped masked
// keys contribute exactly-0 weight, so this is fp-exact up to summation order).
// Structure = the proven 214us pipeline: block (b,h, 128-q tile), 4 waves x 32q,
// cooperative double-buffered LDS K staging, ONE barrier per 64-key tile,
// V direct from global issued early. Changes:
//   - dynamic tile count ntiles = ceil(nv[b]/64) (device-side, grid static).
//   - XCD-aware 1D block swizzle (r3-proven: FETCH 70->12 MB).
//   - pad-free XOR-swizzled Ks/Ps (r0's 72-pad was an 8-way conflict on both
//     kf and P reads: bank = 4*(l15+quad) mod 32 -> 5.2M conflict cycles).
//   - compacted key-mask Mc as MFMA C-init (tail pad = NEGBIG), query mask mq
//     folded identically to the passing kernels (exact quantization repro).
//   - defer-max (THR=4), s_setprio around MFMA clusters.
// ---------------------------------------------------------------------------
__global__ __launch_bounds__(256, 2) void flash_mfma(
    const unsigned short* __restrict__ Qg, const unsigned short* __restrict__ Kg,
    const unsigned short* __restrict__ VtG, const float* __restrict__ Mf,
    const float* __restrict__ Mc, const int* __restrict__ nvalid,
    unsigned short* __restrict__ ctxB)
{
    const int bid = blockIdx.x;                  // 0..511
    const int xcd = bid & 7, idx = bid >> 3;     // XCD x owns bh 4x..4x+3
    const int bh = xcd * 4 + (idx & 3);
    const int q0 = (idx >> 2) * 128;
    const int b = bh >> 3, h = bh & 7;

    const int tid = threadIdx.x;
    const int w = tid >> 6, lane = tid & 63;
    const int l15 = lane & 15, quad = lane >> 4;
    const int swz = l15 & 7;

    __shared__ unsigned short Ks[2][64 * 64];    // pad-free, XOR-chunk-swizzled
    __shared__ unsigned short Ps[4][32 * 64];    // per-wave P, same swizzle
    unsigned short* pw = &Ps[w][0];

    const int nv = nvalid[b];
    int ntiles = (nv + 63) >> 6;
    if (ntiles < 1) ntiles = 1;

    const float* mfb = Mf + b * 2048;
    const float* mcp = Mc + b * 2048 + quad * 4;

    // Q fragments (B-operand) + query mask, resident
    bf16x8 qf[2][2];
    float mq[2];
    #pragma unroll
    for (int qb = 0; qb < 2; qb++) {
        int qrow = q0 + w * 32 + qb * 16 + l15;
        const unsigned short* p = &Qg[((long)bh * 2048 + qrow) * 64 + quad * 8];
        qf[qb][0] = *(const bf16x8*)p;
        qf[qb][1] = *(const bf16x8*)(p + 32);
        mq[qb] = mfb[qrow];
    }

    // V row pointers (bh,d,i layout)
    const unsigned short* vp[4];
    #pragma unroll
    for (int i = 0; i < 4; i++)
        vp[i] = VtG + ((long)bh * 64 + i * 16 + l15) * 2048 + quad * 8;

    // K staging: thread -> (row = tid>>2, chunks (tid&3)*2, +1) of 64x64 tile
    const int srow = tid >> 2;
    const int sch  = (tid & 3) * 2;
    const unsigned short* kgb = Kg + (long)bh * 2048 * 64;
    const int sw0 = srow * 64 + ((sch    ) ^ (srow & 7)) * 8;
    const int sw1 = srow * 64 + ((sch + 1) ^ (srow & 7)) * 8;

    // preamble: stage tile 0 into Ks[0]
    {
        uint4 a = *(const uint4*)&kgb[srow * 64 + sch * 8];
        uint4 c = *(const uint4*)&kgb[srow * 64 + sch * 8 + 8];
        *(uint4*)&Ks[0][sw0] = a;
        *(uint4*)&Ks[0][sw1] = c;
    }

    // swizzled fragment-read chunk offsets (kc=0 -> chunk quad, kc=1 -> 4+quad)
    const int koff0 = ((quad    ) ^ swz) * 8;
    const int koff1 = ((quad + 4) ^ swz) * 8;

    f32x4 accO[2][4];
    #pragma unroll
    for (int qb = 0; qb < 2; qb++)
        #pragma unroll
        for (int dt = 0; dt < 4; dt++) accO[qb][dt] = (f32x4){0.f, 0.f, 0.f, 0.f};
    float mi[2] = {-3.0e38f, -3.0e38f};
    float li[2] = {0.f, 0.f};

    __syncthreads();

    for (int t = 0; t < ntiles; t++) {
        const int kt = t * 64;
        const int ktn = (t + 1 < ntiles) ? kt + 64 : kt;
        const int cur = t & 1, nxt = cur ^ 1;

        // [A] issue global loads: V frags + key-mask for THIS tile, K for NEXT
        bf16x8 vf[4][2];
        #pragma unroll
        for (int dt = 0; dt < 4; dt++) {
            vf[dt][0] = *(const bf16x8*)(vp[dt] + kt);
            vf[dt][1] = *(const bf16x8*)(vp[dt] + kt + 32);
        }
        uint4 kst0 = *(const uint4*)&kgb[(ktn + srow) * 64 + sch * 8];
        uint4 kst1 = *(const uint4*)&kgb[(ktn + srow) * 64 + sch * 8 + 8];
        f32x4 kmf[4];
        #pragma unroll
        for (int nt = 0; nt < 4; nt++)
            kmf[nt] = *(const f32x4*)(mcp + kt + nt * 16);

        // [C] K frags from LDS buf[cur] (swizzled); QK: S^T (rows=key, cols=q)
        bf16x8 kf[4][2];
        #pragma unroll
        for (int nt = 0; nt < 4; nt++) {
            kf[nt][0] = *(const bf16x8*)&Ks[cur][(nt * 16 + l15) * 64 + koff0];
            kf[nt][1] = *(const bf16x8*)&Ks[cur][(nt * 16 + l15) * 64 + koff1];
        }
        f32x4 sc[2][4];
        #pragma unroll
        for (int qb = 0; qb < 2; qb++)
            #pragma unroll
            for (int nt = 0; nt < 4; nt++) {
                f32x4 c = kmf[nt];               // masks as C-init: exact
                c[0] += mq[qb]; c[1] += mq[qb]; c[2] += mq[qb]; c[3] += mq[qb];
                sc[qb][nt] = c;
            }
        __builtin_amdgcn_s_setprio(1);
        #pragma unroll
        for (int qb = 0; qb < 2; qb++)
            #pragma unroll
            for (int nt = 0; nt < 4; nt++) {
                sc[qb][nt] = __builtin_amdgcn_mfma_f32_16x16x32_bf16(
                    kf[nt][0], qf[qb][0], sc[qb][nt], 0, 0, 0);
                sc[qb][nt] = __builtin_amdgcn_mfma_f32_16x16x32_bf16(
                    kf[nt][1], qf[qb][1], sc[qb][nt], 0, 0, 0);
            }
        __builtin_amdgcn_s_setprio(0);

        // [D] online softmax (reduce over keys = in-lane + quad shfls)
        #pragma unroll
        for (int qb = 0; qb < 2; qb++) {
            float mloc = fmaxf(fmaxf(sc[qb][0][0], sc[qb][0][1]),
                               fmaxf(sc[qb][0][2], sc[qb][0][3]));
            #pragma unroll
            for (int nt = 1; nt < 4; nt++)
                mloc = fmaxf(mloc, fmaxf(fmaxf(sc[qb][nt][0], sc[qb][nt][1]),
                                         fmaxf(sc[qb][nt][2], sc[qb][nt][3])));
            mloc = fmaxf(mloc, __shfl_xor(mloc, 16));
            mloc = fmaxf(mloc, __shfl_xor(mloc, 32));

            float mn = mi[qb];
            if (!__all(mloc <= mn + 4.f)) {      // defer-max: P bounded by 2^4
                float mo = mn;
                mn = fmaxf(mo, mloc);
                float alpha = __builtin_amdgcn_exp2f(mo - mn);
                li[qb] *= alpha;
                #pragma unroll
                for (int dt = 0; dt < 4; dt++) {
                    accO[qb][dt][0] *= alpha; accO[qb][dt][1] *= alpha;
                    accO[qb][dt][2] *= alpha; accO[qb][dt][3] *= alpha;
                }
                mi[qb] = mn;
            }

            float ps = 0.f;
            const int prbase = (qb * 16 + l15) * 64;
            #pragma unroll
            for (int nt = 0; nt < 4; nt++) {
                float p0 = __builtin_amdgcn_exp2f(sc[qb][nt][0] - mn);
                float p1 = __builtin_amdgcn_exp2f(sc[qb][nt][1] - mn);
                float p2 = __builtin_amdgcn_exp2f(sc[qb][nt][2] - mn);
                float p3 = __builtin_amdgcn_exp2f(sc[qb][nt][3] - mn);
                ps += (p0 + p1) + (p2 + p3);
                // keys nt*16+quad*4..+3 -> chunk 2nt+(quad>>1), sub (quad&1)*4
                uint2 pp;
                pp.x = pack_rn(p0, p1);
                pp.y = pack_rn(p2, p3);
                *(uint2*)&pw[prbase + ((2 * nt + (quad >> 1)) ^ swz) * 8 + (quad & 1) * 4] = pp;
            }
            ps += __shfl_xor(ps, 16);
            ps += __shfl_xor(ps, 32);
            li[qb] += ps;
        }

        // [E] PV: O^T += Vt (A) x P^T (B)
        #pragma unroll
        for (int qb = 0; qb < 2; qb++) {
            bf16x8 pf0 = *(const bf16x8*)&pw[(qb * 16 + l15) * 64 + koff0];
            bf16x8 pf1 = *(const bf16x8*)&pw[(qb * 16 + l15) * 64 + koff1];
            __builtin_amdgcn_s_setprio(1);
            #pragma unroll
            for (int dt = 0; dt < 4; dt++) {
                accO[qb][dt] = __builtin_amdgcn_mfma_f32_16x16x32_bf16(
                    vf[dt][0], pf0, accO[qb][dt], 0, 0, 0);
                accO[qb][dt] = __builtin_amdgcn_mfma_f32_16x16x32_bf16(
                    vf[dt][1], pf1, accO[qb][dt], 0, 0, 0);
            }
            __builtin_amdgcn_s_setprio(0);
        }

        // [F] commit next K tile to LDS (waits the [A] loads), [G] barrier
        *(uint4*)&Ks[nxt][sw0] = kst0;
        *(uint4*)&Ks[nxt][sw1] = kst1;
        __syncthreads();
    }

    #pragma unroll
    for (int qb = 0; qb < 2; qb++) {
        float inv = 1.f / li[qb];
        int q = q0 + w * 32 + qb * 16 + l15;
        int obase = (b * 2048 + q) * 512 + h * 64 + quad * 4;
        #pragma unroll
        for (int dt = 0; dt < 4; dt++) {
            uint2 o;
            o.x = pack_rn(accO[qb][dt][0] * inv, accO[qb][dt][1] * inv);
            o.y = pack_rn(accO[qb][dt][2] * inv, accO[qb][dt][3] * inv);
            *(uint2*)&ctxB[obase + dt * 16] = o;
        }
    }
}

// ---------------------------------------------------------------------------
// Output projection: out(fp32) = ctx_bf16 @ Wo + bo.
// ---------------------------------------------------------------------------
__global__ __launch_bounds__(256) void proj_out_mfma(
    const unsigned short* __restrict__ ctxB, const unsigned short* __restrict__ Wto,
    const float* __restrict__ bo, float* __restrict__ out)
{
    const int m0 = blockIdx.y * 128, n0 = blockIdx.x * 128;
    const int tid = threadIdx.x;
    const int w = tid >> 6, lane = tid & 63;
    const int l15 = lane & 15, quad = lane >> 4;
    const int wm = (w >> 1) * 64, wn = (w & 1) * 64;

    __shared__ unsigned short As[128 * 72];
    __shared__ unsigned short Bs[128 * 72];

    f32x4 acc[4][4];
    #pragma unroll
    for (int i = 0; i < 4; i++)
        #pragma unroll
        for (int j = 0; j < 4; j++) acc[i][j] = (f32x4){0.f, 0.f, 0.f, 0.f};

    for (int k0 = 0; k0 < 512; k0 += 64) {
        __syncthreads();
        #pragma unroll
        for (int it = 0; it < 2; it++) {
            int lin = tid + it * 256;
            int row = lin >> 2, c2 = (lin & 3) * 2;
            *(uint4*)&As[row * 72 + c2 * 8]     = *(const uint4*)&Wto[(m0 + row) * 512 + k0 + c2 * 8];
            *(uint4*)&As[row * 72 + c2 * 8 + 8] = *(const uint4*)&Wto[(m0 + row) * 512 + k0 + c2 * 8 + 8];
            *(uint4*)&Bs[row * 72 + c2 * 8]     = *(const uint4*)&ctxB[(n0 + row) * 512 + k0 + c2 * 8];
            *(uint4*)&Bs[row * 72 + c2 * 8 + 8] = *(const uint4*)&ctxB[(n0 + row) * 512 + k0 + c2 * 8 + 8];
        }
        __syncthreads();
        #pragma unroll
        for (int kc = 0; kc < 2; kc++) {
            bf16x8 a[4], bb[4];
            #pragma unroll
            for (int i = 0; i < 4; i++)
                a[i] = *(const bf16x8*)&As[(wm + 16 * i + l15) * 72 + kc * 32 + quad * 8];
            #pragma unroll
            for (int j = 0; j < 4; j++)
                bb[j] = *(const bf16x8*)&Bs[(wn + 16 * j + l15) * 72 + kc * 32 + quad * 8];
            #pragma unroll
            for (int i = 0; i < 4; i++)
                #pragma unroll
                for (int j = 0; j < 4; j++)
                    acc[i][j] = __builtin_amdgcn_mfma_f32_16x16x32_bf16(a[i], bb[j], acc[i][j], 0, 0, 0);
        }
    }

    #pragma unroll
    for (int j = 0; j < 4; j++) {
        int sg = n0 + wn + 16 * j + l15;
        #pragma unroll
        for (int i = 0; i < 4; i++) {
            int F = m0 + wm + 16 * i + quad * 4;
            float4 b4 = *(const float4*)&bo[F];
            float4 vv;
            vv.x = acc[i][j][0] + b4.x;
            vv.y = acc[i][j][1] + b4.y;
            vv.z = acc[i][j][2] + b4.z;
            vv.w = acc[i][j][3] + b4.w;
            *(float4*)&out[sg * 512 + F] = vv;
        }
    }
}

extern "C" void kernel_launch(void* const* d_in, const int* in_sizes, int n_in,
                              void* d_out, int out_size, void* d_ws, size_t ws_size,
                              hipStream_t stream)
{
    const float* query = (const float*)d_in[0];
    const float* value = (const float*)d_in[1];
    const int*   amask = (const int*)d_in[2];
    const float* Wq = (const float*)d_in[3];
    const float* bq = (const float*)d_in[4];
    const float* Wk = (const float*)d_in[5];
    const float* bk = (const float*)d_in[6];
    const float* Wv = (const float*)d_in[7];
    const float* bv = (const float*)d_in[8];
    const float* Wo = (const float*)d_in[9];
    const float* bo = (const float*)d_in[10];
    float* out = (float*)d_out;

    char* ws = (char*)d_ws;
    const size_t MB = 1 << 20;
    const size_t KB = 1 << 10;
    unsigned short* Xbq = (unsigned short*)(ws);                  // 8 MB bf16
    unsigned short* Xbv = (unsigned short*)(ws + 8 * MB);         // 8 MB
    unsigned short* Wtq = (unsigned short*)(ws + 16 * MB);        // 0.5 MB each
    unsigned short* Wtk = (unsigned short*)(ws + 16 * MB + MB / 2);
    unsigned short* Wtv = (unsigned short*)(ws + 17 * MB);
    unsigned short* Wto = (unsigned short*)(ws + 17 * MB + MB / 2);
    unsigned short* Qb  = (unsigned short*)(ws + 18 * MB);        // 8 MB (bh,s,d)
    unsigned short* Kb  = (unsigned short*)(ws + 26 * MB);        // 8 MB (bh,i,d) compacted
    unsigned short* VtG = (unsigned short*)(ws + 34 * MB);        // 8 MB (bh,d,i) compacted
    unsigned short* ctx = (unsigned short*)(ws + 42 * MB);        // 8 MB (b*s, h*d)

    // aux region 1 (inside ctx, dead until flash overwrites it):
    //   written by compact_k BEFORE proj; read by proj staging.
    int*   idx1 = (int*)(ws + 42 * MB);                           // 32 KB
    int*   nv1  = (int*)(ws + 42 * MB + 32 * KB);                 // 16 B
    // aux region 2 (inside Xbq, dead after proj_qkv; written by mask_fc):
    float* Mf   = (float*)(ws);                                   // 32 KB
    float* Mc   = (float*)(ws + 32 * KB);                         // 32 KB
    int*   nv2  = (int*)(ws + 64 * KB);                           // 16 B

    cast_x<<<dim3(2048, 1, 2), 256, 0, stream>>>(query, value, Xbq, Xbv);
    cast_wt<<<dim3(8, 8, 4), 256, 0, stream>>>(Wq, Wk, Wv, Wo, Wtq, Wtk, Wtv, Wto);
    compact_k<<<dim3(1), 256, 0, stream>>>(amask, idx1, nv1);
    proj_qkv_mfma<<<dim3(64, 4, 3), 256, 0, stream>>>(Xbq, Xbv, Wtq, Wtk, Wtv,
                                                      bq, bk, bv, idx1, nv1,
                                                      Qb, Kb, VtG);
    mask_fc<<<dim3(8), 256, 0, stream>>>(amask, nv1, Mf, Mc, nv2);
    flash_mfma<<<dim3(512), 256, 0, stream>>>(Qb, Kb, VtG, Mf, Mc, nv2, ctx);
    proj_out_mfma<<<dim3(64, 4), 256, 0, stream>>>(ctx, Wto, bo, out);
}

// Round 5
// 187.578 us; speedup vs baseline: 1.5111x; 1.1335x over previous
//
#include <hip/hip_runtime.h>

#define B_ 4
#define S_ 2048
#define D_ 512
#define H_ 8

typedef __attribute__((ext_vector_type(8))) __bf16 bf16x8;
typedef __attribute__((ext_vector_type(4))) float f32x4;

#define NEGBIG  -1.442695040e9f          // -1e9 * log2(e): masks live in exp2 domain
#define QSCALE  0.18033688011112042f     // 0.125 * log2(e) folded into Q

// pack two floats -> two bf16 (RNE-ish, ties-up): 2 adds + 1 v_perm
__device__ __forceinline__ unsigned pack_rn(float a, float b) {
    union { float f; unsigned u; } ua, ub; ua.f = a; ub.f = b;
    return __builtin_amdgcn_perm(ub.u + 0x8000u, ua.u + 0x8000u, 0x07060302u);
}

// async global->LDS, 16B per lane. LDS dest = wave-uniform base + lane*16.
__device__ __forceinline__ void gl16(const void* g, void* l) {
    __builtin_amdgcn_global_load_lds(
        (const __attribute__((address_space(1))) unsigned int*)g,
        (__attribute__((address_space(3))) unsigned int*)l, 16, 0, 0);
}

// ---------------------------------------------------------------------------
// Fused preprocessing (one launch):
//   bid <  4096 : cast_x  — fp32->bf16 cast of query/value activations
//   bid <  4352 : cast_wt — coalesced weight cast+transpose via LDS tile
//   bid == 4352 : compact+mask — per-batch key compaction (prefetched ballot
//                 scan: 32 independent loads first, then pure-ALU scan) +
//                 exp2-domain fp32 masks. idxc tail padded with 0 so proj
//                 needs no zero-fill (pad rows masked exactly by Mc).
// ---------------------------------------------------------------------------
__global__ __launch_bounds__(256) void pre_all(
    const float* __restrict__ q, const float* __restrict__ v,
    const int* __restrict__ am,
    const float* __restrict__ Wq, const float* __restrict__ Wk,
    const float* __restrict__ Wv, const float* __restrict__ Wo,
    unsigned short* __restrict__ xq, unsigned short* __restrict__ xv,
    unsigned short* __restrict__ Tq, unsigned short* __restrict__ Tk,
    unsigned short* __restrict__ Tv, unsigned short* __restrict__ To,
    int* __restrict__ idxc, int* __restrict__ nvout,
    float* __restrict__ Mf, float* __restrict__ Mc)
{
    const int bid = blockIdx.x;
    const int tid = threadIdx.x;

    if (bid < 4096) {                       // ---- cast_x ----
        const int z = bid >> 11, xb = bid & 2047;
        const float* src = z ? v : q;
        unsigned short* dst = z ? xv : xq;
        int i = (xb * 256 + tid) * 8;
        float4 f0 = *(const float4*)&src[i];
        float4 f1 = *(const float4*)&src[i + 4];
        uint4 o;
        o.x = pack_rn(f0.x, f0.y); o.y = pack_rn(f0.z, f0.w);
        o.z = pack_rn(f1.x, f1.y); o.w = pack_rn(f1.z, f1.w);
        *(uint4*)&dst[i] = o;
    } else if (bid < 4352) {                // ---- cast_wt ----
        int r = bid - 4096;
        int z = r >> 6, rem = r & 63;
        const float* W = (z == 0) ? Wq : (z == 1) ? Wk : (z == 2) ? Wv : Wo;
        unsigned short* T = (z == 0) ? Tq : (z == 1) ? Tk : (z == 2) ? Tv : To;
        int n0 = (rem & 7) * 64, k0 = (rem >> 3) * 64;

        __shared__ float Ts[64][69];
        #pragma unroll
        for (int it = 0; it < 4; it++) {
            int lin = tid + it * 256;
            int kr = lin >> 4, c4 = (lin & 15) * 4;
            float4 vv = *(const float4*)&W[(k0 + kr) * 512 + n0 + c4];
            Ts[kr][c4 + 0] = vv.x; Ts[kr][c4 + 1] = vv.y;
            Ts[kr][c4 + 2] = vv.z; Ts[kr][c4 + 3] = vv.w;
        }
        __syncthreads();
        int n = tid >> 2, kc = tid & 3;
        unsigned p[8];
        #pragma unroll
        for (int j = 0; j < 8; j++)
            p[j] = pack_rn(Ts[kc * 16 + 2 * j][n], Ts[kc * 16 + 2 * j + 1][n]);
        unsigned short* dst = &T[(n0 + n) * 512 + k0 + kc * 16];
        *(uint4*)dst       = *(uint4*)&p[0];
        *(uint4*)(dst + 8) = *(uint4*)&p[4];
    } else {                                // ---- compact + masks ----
        const int w = tid >> 6, lane = tid & 63;   // wave w = batch w
        const int* amb = am + w * 2048;
        int m[32];
        #pragma unroll
        for (int s = 0; s < 32; s++) m[s] = amb[s * 64 + lane];  // all issued up front

        int* ib = idxc + w * 2048;
        const unsigned long long lt = (1ULL << lane) - 1ULL;
        int base = 0;
        #pragma unroll
        for (int s = 0; s < 32; s++) {
            unsigned long long bal = __ballot(m[s] != 0);
            if (m[s]) ib[base + __popcll(bal & lt)] = s * 64 + lane;
            base += __popcll(bal);
        }
        const int nv = base;
        for (int i = nv + lane; i < 2048; i += 64) ib[i] = 0;   // pad -> row 0
        float* mfb = Mf + w * 2048;
        float* mcb = Mc + w * 2048;
        #pragma unroll
        for (int s = 0; s < 32; s++) {
            int i = s * 64 + lane;
            mfb[i] = m[s] ? 0.f : NEGBIG;
            mcb[i] = (i < nv) ? 0.f : NEGBIG;
        }
        if (lane == 0) nvout[w] = nv;
    }
}

// ---------------------------------------------------------------------------
// QKV projection GEMM with fused key-compaction gather.
// Staging via global_load_lds (16B/lane), pad-free [128][64] LDS with
// XOR-chunk swizzle: LDS[row][c] holds global chunk (c ^ (row&7)); the
// swizzle is applied on the SOURCE address (rule 21) and undone on the
// fragment read -> conflict-free ds_read_b128 (was 8-way on the 72-pad).
// z=0 (Q): A=Wtq (m=feature), B=Xq (n=s, full) -> (bh,s,d), scaled.
// z=1 (K): A=Wtk, B=Xv gathered by idxc (n=compacted s) -> (bh,i,d).
// z=2 (V): A=Xv gathered, B=Wtv -> (bh,d,i).
// Blocks entirely beyond roundup128(nv) exit early. idxc tail = 0 -> pad
// rows are proj(x0), finite, masked exactly by Mc in flash.
// ---------------------------------------------------------------------------
__global__ __launch_bounds__(256) void proj_qkv_mfma(
    const unsigned short* __restrict__ Xq, const unsigned short* __restrict__ Xv,
    const unsigned short* __restrict__ Wtq, const unsigned short* __restrict__ Wtk,
    const unsigned short* __restrict__ Wtv,
    const float* __restrict__ bq, const float* __restrict__ bk,
    const float* __restrict__ bv,
    const int* __restrict__ idxc, const int* __restrict__ nv1,
    unsigned short* __restrict__ Qb, unsigned short* __restrict__ Kb,
    unsigned short* __restrict__ VtG)
{
    const int z = blockIdx.z;
    const unsigned short* A  = (z == 0) ? Wtq : (z == 1) ? Wtk : Xv;
    const unsigned short* Bm = (z == 0) ? Xq  : (z == 1) ? Xv  : Wtv;
    const float* bias        = (z == 0) ? bq  : (z == 1) ? bk  : bv;
    const int m0 = (z < 2) ? blockIdx.y * 128 : blockIdx.x * 128;
    const int n0 = (z < 2) ? blockIdx.x * 128 : blockIdx.y * 128;

    // early-exit for blocks entirely in the dead compacted region
    if (z == 1) {
        int bb = n0 >> 11, cap = (nv1[bb] + 127) & ~127;
        if (cap < 128) cap = 128;
        if ((n0 & 2047) >= cap) return;
    }
    if (z == 2) {
        int bb = m0 >> 11, cap = (nv1[bb] + 127) & ~127;
        if (cap < 128) cap = 128;
        if ((m0 & 2047) >= cap) return;
    }

    const int tid = threadIdx.x;
    const int w = tid >> 6, lane = tid & 63;
    const int l15 = lane & 15, quad = lane >> 4;
    const int wm = (w >> 1) * 64, wn = (w & 1) * 64;

    __shared__ unsigned short As[128 * 64];
    __shared__ unsigned short Bs[128 * 64];

    // staging geometry: issue is covers rows is*32 + (tid>>3); chunk source
    // is pre-swizzled so LDS content matches the XOR layout.
    const int srw  = tid >> 3;                       // 0..31
    const int csrc = (tid & 7) ^ (srw & 7);
    const unsigned short* aS[4];
    const unsigned short* bS[4];
    unsigned short* la[4];
    unsigned short* lb[4];
    #pragma unroll
    for (int is = 0; is < 4; is++) {
        int ra = m0 + is * 32 + srw;
        int rb = n0 + is * 32 + srw;
        long sa = ra, sb = rb;
        if (z == 2) { int bb = ra >> 11; sa = (long)bb * 2048 + idxc[bb * 2048 + (ra & 2047)]; }
        if (z == 1) { int bb = rb >> 11; sb = (long)bb * 2048 + idxc[bb * 2048 + (rb & 2047)]; }
        aS[is] = A  + sa * 512 + csrc * 8;
        bS[is] = Bm + sb * 512 + csrc * 8;
        la[is] = &As[is * 2048 + w * 512];           // wave-uniform LDS bases
        lb[is] = &Bs[is * 2048 + w * 512];
    }

    const int koff0 = ((quad    ) ^ (l15 & 7)) * 8;  // undo swizzle on read
    const int koff1 = ((quad + 4) ^ (l15 & 7)) * 8;

    f32x4 acc[4][4];
    #pragma unroll
    for (int i = 0; i < 4; i++)
        #pragma unroll
        for (int j = 0; j < 4; j++) acc[i][j] = (f32x4){0.f, 0.f, 0.f, 0.f};

    for (int k0 = 0; k0 < 512; k0 += 64) {
        __syncthreads();
        #pragma unroll
        for (int is = 0; is < 4; is++) {
            gl16(aS[is] + k0, la[is]);
            gl16(bS[is] + k0, lb[is]);
        }
        __syncthreads();                             // drains vmcnt
        #pragma unroll
        for (int kc = 0; kc < 2; kc++) {
            const int ko = kc ? koff1 : koff0;
            bf16x8 a[4], bb[4];
            #pragma unroll
            for (int i = 0; i < 4; i++)
                a[i] = *(const bf16x8*)&As[(wm + 16 * i + l15) * 64 + ko];
            #pragma unroll
            for (int j = 0; j < 4; j++)
                bb[j] = *(const bf16x8*)&Bs[(wn + 16 * j + l15) * 64 + ko];
            #pragma unroll
            for (int i = 0; i < 4; i++)
                #pragma unroll
                for (int j = 0; j < 4; j++)
                    acc[i][j] = __builtin_amdgcn_mfma_f32_16x16x32_bf16(a[i], bb[j], acc[i][j], 0, 0, 0);
        }
    }

    if (z == 2) {
        // V: cols = feature, rows = compacted s. ushort4 along s into (bh,d,i).
        #pragma unroll
        for (int j = 0; j < 4; j++) {
            int N = n0 + wn + 16 * j + l15;
            float bv_ = bias[N];
            int h = N >> 6, d = N & 63;
            #pragma unroll
            for (int i = 0; i < 4; i++) {
                int Mb = m0 + wm + 16 * i + quad * 4;
                int b = Mb >> 11, s = Mb & 2047;
                uint2 o;
                o.x = pack_rn(acc[i][j][0] + bv_, acc[i][j][1] + bv_);
                o.y = pack_rn(acc[i][j][2] + bv_, acc[i][j][3] + bv_);
                *(uint2*)&VtG[((b * H_ + h) * 64 + d) * 2048 + s] = o;
            }
        }
    } else {
        // Q/K: cols = s (K: compacted), rows = feature. ushort4 along d.
        unsigned short* dst = (z == 0) ? Qb : Kb;
        const float scale = (z == 0) ? QSCALE : 1.0f;
        #pragma unroll
        for (int j = 0; j < 4; j++) {
            int sg = n0 + wn + 16 * j + l15;
            int b = sg >> 11, s = sg & 2047;
            #pragma unroll
            for (int i = 0; i < 4; i++) {
                int F = m0 + wm + 16 * i + quad * 4;
                int h = F >> 6, d = F & 63;
                float4 b4 = *(const float4*)&bias[F];
                uint2 o;
                o.x = pack_rn((acc[i][j][0] + b4.x) * scale, (acc[i][j][1] + b4.y) * scale);
                o.y = pack_rn((acc[i][j][2] + b4.z) * scale, (acc[i][j][3] + b4.w) * scale);
                *(uint2*)&dst[((b * H_ + h) * 2048 + s) * 64 + d] = o;
            }
        }
    }
}

// ---------------------------------------------------------------------------
// MFMA flash attention over COMPACTED keys — UNCHANGED from the verified
// 51us/212us round-4 kernel (compaction + XOR-swizzled LDS + XCD swizzle +
// defer-max + setprio). See round-4 notes.
// ---------------------------------------------------------------------------
__global__ __launch_bounds__(256, 2) void flash_mfma(
    const unsigned short* __restrict__ Qg, const unsigned short* __restrict__ Kg,
    const unsigned short* __restrict__ VtG, const float* __restrict__ Mf,
    const float* __restrict__ Mc, const int* __restrict__ nvalid,
    unsigned short* __restrict__ ctxB)
{
    const int bid = blockIdx.x;                  // 0..511
    const int xcd = bid & 7, idx = bid >> 3;     // XCD x owns bh 4x..4x+3
    const int bh = xcd * 4 + (idx & 3);
    const int q0 = (idx >> 2) * 128;
    const int b = bh >> 3, h = bh & 7;

    const int tid = threadIdx.x;
    const int w = tid >> 6, lane = tid & 63;
    const int l15 = lane & 15, quad = lane >> 4;
    const int swz = l15 & 7;

    __shared__ unsigned short Ks[2][64 * 64];    // pad-free, XOR-chunk-swizzled
    __shared__ unsigned short Ps[4][32 * 64];    // per-wave P, same swizzle
    unsigned short* pw = &Ps[w][0];

    const int nv = nvalid[b];
    int ntiles = (nv + 63) >> 6;
    if (ntiles < 1) ntiles = 1;

    const float* mfb = Mf + b * 2048;
    const float* mcp = Mc + b * 2048 + quad * 4;

    // Q fragments (B-operand) + query mask, resident
    bf16x8 qf[2][2];
    float mq[2];
    #pragma unroll
    for (int qb = 0; qb < 2; qb++) {
        int qrow = q0 + w * 32 + qb * 16 + l15;
        const unsigned short* p = &Qg[((long)bh * 2048 + qrow) * 64 + quad * 8];
        qf[qb][0] = *(const bf16x8*)p;
        qf[qb][1] = *(const bf16x8*)(p + 32);
        mq[qb] = mfb[qrow];
    }

    // V row pointers (bh,d,i layout)
    const unsigned short* vp[4];
    #pragma unroll
    for (int i = 0; i < 4; i++)
        vp[i] = VtG + ((long)bh * 64 + i * 16 + l15) * 2048 + quad * 8;

    // K staging: thread -> (row = tid>>2, chunks (tid&3)*2, +1) of 64x64 tile
    const int srow = tid >> 2;
    const int sch  = (tid & 3) * 2;
    const unsigned short* kgb = Kg + (long)bh * 2048 * 64;
    const int sw0 = srow * 64 + ((sch    ) ^ (srow & 7)) * 8;
    const int sw1 = srow * 64 + ((sch + 1) ^ (srow & 7)) * 8;

    // preamble: stage tile 0 into Ks[0]
    {
        uint4 a = *(const uint4*)&kgb[srow * 64 + sch * 8];
        uint4 c = *(const uint4*)&kgb[srow * 64 + sch * 8 + 8];
        *(uint4*)&Ks[0][sw0] = a;
        *(uint4*)&Ks[0][sw1] = c;
    }

    // swizzled fragment-read chunk offsets (kc=0 -> chunk quad, kc=1 -> 4+quad)
    const int koff0 = ((quad    ) ^ swz) * 8;
    const int koff1 = ((quad + 4) ^ swz) * 8;

    f32x4 accO[2][4];
    #pragma unroll
    for (int qb = 0; qb < 2; qb++)
        #pragma unroll
        for (int dt = 0; dt < 4; dt++) accO[qb][dt] = (f32x4){0.f, 0.f, 0.f, 0.f};
    float mi[2] = {-3.0e38f, -3.0e38f};
    float li[2] = {0.f, 0.f};

    __syncthreads();

    for (int t = 0; t < ntiles; t++) {
        const int kt = t * 64;
        const int ktn = (t + 1 < ntiles) ? kt + 64 : kt;
        const int cur = t & 1, nxt = cur ^ 1;

        // [A] issue global loads: V frags + key-mask for THIS tile, K for NEXT
        bf16x8 vf[4][2];
        #pragma unroll
        for (int dt = 0; dt < 4; dt++) {
            vf[dt][0] = *(const bf16x8*)(vp[dt] + kt);
            vf[dt][1] = *(const bf16x8*)(vp[dt] + kt + 32);
        }
        uint4 kst0 = *(const uint4*)&kgb[(ktn + srow) * 64 + sch * 8];
        uint4 kst1 = *(const uint4*)&kgb[(ktn + srow) * 64 + sch * 8 + 8];
        f32x4 kmf[4];
        #pragma unroll
        for (int nt = 0; nt < 4; nt++)
            kmf[nt] = *(const f32x4*)(mcp + kt + nt * 16);

        // [C] K frags from LDS buf[cur] (swizzled); QK: S^T (rows=key, cols=q)
        bf16x8 kf[4][2];
        #pragma unroll
        for (int nt = 0; nt < 4; nt++) {
            kf[nt][0] = *(const bf16x8*)&Ks[cur][(nt * 16 + l15) * 64 + koff0];
            kf[nt][1] = *(const bf16x8*)&Ks[cur][(nt * 16 + l15) * 64 + koff1];
        }
        f32x4 sc[2][4];
        #pragma unroll
        for (int qb = 0; qb < 2; qb++)
            #pragma unroll
            for (int nt = 0; nt < 4; nt++) {
                f32x4 c = kmf[nt];               // masks as C-init: exact
                c[0] += mq[qb]; c[1] += mq[qb]; c[2] += mq[qb]; c[3] += mq[qb];
                sc[qb][nt] = c;
            }
        __builtin_amdgcn_s_setprio(1);
        #pragma unroll
        for (int qb = 0; qb < 2; qb++)
            #pragma unroll
            for (int nt = 0; nt < 4; nt++) {
                sc[qb][nt] = __builtin_amdgcn_mfma_f32_16x16x32_bf16(
                    kf[nt][0], qf[qb][0], sc[qb][nt], 0, 0, 0);
                sc[qb][nt] = __builtin_amdgcn_mfma_f32_16x16x32_bf16(
                    kf[nt][1], qf[qb][1], sc[qb][nt], 0, 0, 0);
            }
        __builtin_amdgcn_s_setprio(0);

        // [D] online softmax (reduce over keys = in-lane + quad shfls)
        #pragma unroll
        for (int qb = 0; qb < 2; qb++) {
            float mloc = fmaxf(fmaxf(sc[qb][0][0], sc[qb][0][1]),
                               fmaxf(sc[qb][0][2], sc[qb][0][3]));
            #pragma unroll
            for (int nt = 1; nt < 4; nt++)
                mloc = fmaxf(mloc, fmaxf(fmaxf(sc[qb][nt][0], sc[qb][nt][1]),
                                         fmaxf(sc[qb][nt][2], sc[qb][nt][3])));
            mloc = fmaxf(mloc, __shfl_xor(mloc, 16));
            mloc = fmaxf(mloc, __shfl_xor(mloc, 32));

            float mn = mi[qb];
            if (!__all(mloc <= mn + 4.f)) {      // defer-max: P bounded by 2^4
                float mo = mn;
                mn = fmaxf(mo, mloc);
                float alpha = __builtin_amdgcn_exp2f(mo - mn);
                li[qb] *= alpha;
                #pragma unroll
                for (int dt = 0; dt < 4; dt++) {
                    accO[qb][dt][0] *= alpha; accO[qb][dt][1] *= alpha;
                    accO[qb][dt][2] *= alpha; accO[qb][dt][3] *= alpha;
                }
                mi[qb] = mn;
            }

            float ps = 0.f;
            const int prbase = (qb * 16 + l15) * 64;
            #pragma unroll
            for (int nt = 0; nt < 4; nt++) {
                float p0 = __builtin_amdgcn_exp2f(sc[qb][nt][0] - mn);
                float p1 = __builtin_amdgcn_exp2f(sc[qb][nt][1] - mn);
                float p2 = __builtin_amdgcn_exp2f(sc[qb][nt][2] - mn);
                float p3 = __builtin_amdgcn_exp2f(sc[qb][nt][3] - mn);
                ps += (p0 + p1) + (p2 + p3);
                // keys nt*16+quad*4..+3 -> chunk 2nt+(quad>>1), sub (quad&1)*4
                uint2 pp;
                pp.x = pack_rn(p0, p1);
                pp.y = pack_rn(p2, p3);
                *(uint2*)&pw[prbase + ((2 * nt + (quad >> 1)) ^ swz) * 8 + (quad & 1) * 4] = pp;
            }
            ps += __shfl_xor(ps, 16);
            ps += __shfl_xor(ps, 32);
            li[qb] += ps;
        }

        // [E] PV: O^T += Vt (A) x P^T (B)
        #pragma unroll
        for (int qb = 0; qb < 2; qb++) {
            bf16x8 pf0 = *(const bf16x8*)&pw[(qb * 16 + l15) * 64 + koff0];
            bf16x8 pf1 = *(const bf16x8*)&pw[(qb * 16 + l15) * 64 + koff1];
            __builtin_amdgcn_s_setprio(1);
            #pragma unroll
            for (int dt = 0; dt < 4; dt++) {
                accO[qb][dt] = __builtin_amdgcn_mfma_f32_16x16x32_bf16(
                    vf[dt][0], pf0, accO[qb][dt], 0, 0, 0);
                accO[qb][dt] = __builtin_amdgcn_mfma_f32_16x16x32_bf16(
                    vf[dt][1], pf1, accO[qb][dt], 0, 0, 0);
            }
            __builtin_amdgcn_s_setprio(0);
        }

        // [F] commit next K tile to LDS (waits the [A] loads), [G] barrier
        *(uint4*)&Ks[nxt][sw0] = kst0;
        *(uint4*)&Ks[nxt][sw1] = kst1;
        __syncthreads();
    }

    #pragma unroll
    for (int qb = 0; qb < 2; qb++) {
        float inv = 1.f / li[qb];
        int q = q0 + w * 32 + qb * 16 + l15;
        int obase = (b * 2048 + q) * 512 + h * 64 + quad * 4;
        #pragma unroll
        for (int dt = 0; dt < 4; dt++) {
            uint2 o;
            o.x = pack_rn(accO[qb][dt][0] * inv, accO[qb][dt][1] * inv);
            o.y = pack_rn(accO[qb][dt][2] * inv, accO[qb][dt][3] * inv);
            *(uint2*)&ctxB[obase + dt * 16] = o;
        }
    }
}

// ---------------------------------------------------------------------------
// Output projection: out(fp32) = ctx_bf16 @ Wo + bo.
// Same gload_lds + XOR-swizzle staging as proj_qkv.
// ---------------------------------------------------------------------------
__global__ __launch_bounds__(256) void proj_out_mfma(
    const unsigned short* __restrict__ ctxB, const unsigned short* __restrict__ Wto,
    const float* __restrict__ bo, float* __restrict__ out)
{
    const int m0 = blockIdx.y * 128, n0 = blockIdx.x * 128;
    const int tid = threadIdx.x;
    const int w = tid >> 6, lane = tid & 63;
    const int l15 = lane & 15, quad = lane >> 4;
    const int wm = (w >> 1) * 64, wn = (w & 1) * 64;

    __shared__ unsigned short As[128 * 64];
    __shared__ unsigned short Bs[128 * 64];

    const int srw  = tid >> 3;
    const int csrc = (tid & 7) ^ (srw & 7);
    const unsigned short* aS[4];
    const unsigned short* bS[4];
    unsigned short* la[4];
    unsigned short* lb[4];
    #pragma unroll
    for (int is = 0; is < 4; is++) {
        aS[is] = Wto  + (long)(m0 + is * 32 + srw) * 512 + csrc * 8;
        bS[is] = ctxB + (long)(n0 + is * 32 + srw) * 512 + csrc * 8;
        la[is] = &As[is * 2048 + w * 512];
        lb[is] = &Bs[is * 2048 + w * 512];
    }
    const int koff0 = ((quad    ) ^ (l15 & 7)) * 8;
    const int koff1 = ((quad + 4) ^ (l15 & 7)) * 8;

    f32x4 acc[4][4];
    #pragma unroll
    for (int i = 0; i < 4; i++)
        #pragma unroll
        for (int j = 0; j < 4; j++) acc[i][j] = (f32x4){0.f, 0.f, 0.f, 0.f};

    for (int k0 = 0; k0 < 512; k0 += 64) {
        __syncthreads();
        #pragma unroll
        for (int is = 0; is < 4; is++) {
            gl16(aS[is] + k0, la[is]);
            gl16(bS[is] + k0, lb[is]);
        }
        __syncthreads();
        #pragma unroll
        for (int kc = 0; kc < 2; kc++) {
            const int ko = kc ? koff1 : koff0;
            bf16x8 a[4], bb[4];
            #pragma unroll
            for (int i = 0; i < 4; i++)
                a[i] = *(const bf16x8*)&As[(wm + 16 * i + l15) * 64 + ko];
            #pragma unroll
            for (int j = 0; j < 4; j++)
                bb[j] = *(const bf16x8*)&Bs[(wn + 16 * j + l15) * 64 + ko];
            #pragma unroll
            for (int i = 0; i < 4; i++)
                #pragma unroll
                for (int j = 0; j < 4; j++)
                    acc[i][j] = __builtin_amdgcn_mfma_f32_16x16x32_bf16(a[i], bb[j], acc[i][j], 0, 0, 0);
        }
    }

    #pragma unroll
    for (int j = 0; j < 4; j++) {
        int sg = n0 + wn + 16 * j + l15;
        #pragma unroll
        for (int i = 0; i < 4; i++) {
            int F = m0 + wm + 16 * i + quad * 4;
            float4 b4 = *(const float4*)&bo[F];
            float4 vv;
            vv.x = acc[i][j][0] + b4.x;
            vv.y = acc[i][j][1] + b4.y;
            vv.z = acc[i][j][2] + b4.z;
            vv.w = acc[i][j][3] + b4.w;
            *(float4*)&out[sg * 512 + F] = vv;
        }
    }
}

extern "C" void kernel_launch(void* const* d_in, const int* in_sizes, int n_in,
                              void* d_out, int out_size, void* d_ws, size_t ws_size,
                              hipStream_t stream)
{
    const float* query = (const float*)d_in[0];
    const float* value = (const float*)d_in[1];
    const int*   amask = (const int*)d_in[2];
    const float* Wq = (const float*)d_in[3];
    const float* bq = (const float*)d_in[4];
    const float* Wk = (const float*)d_in[5];
    const float* bk = (const float*)d_in[6];
    const float* Wv = (const float*)d_in[7];
    const float* bv = (const float*)d_in[8];
    const float* Wo = (const float*)d_in[9];
    const float* bo = (const float*)d_in[10];
    float* out = (float*)d_out;

    char* ws = (char*)d_ws;
    const size_t MB = 1 << 20;
    const size_t KB = 1 << 10;
    unsigned short* Xbq = (unsigned short*)(ws);                  // 8 MB bf16
    unsigned short* Xbv = (unsigned short*)(ws + 8 * MB);         // 8 MB
    unsigned short* Wtq = (unsigned short*)(ws + 16 * MB);        // 0.5 MB each
    unsigned short* Wtk = (unsigned short*)(ws + 16 * MB + MB / 2);
    unsigned short* Wtv = (unsigned short*)(ws + 17 * MB);
    unsigned short* Wto = (unsigned short*)(ws + 17 * MB + MB / 2);
    unsigned short* Qb  = (unsigned short*)(ws + 18 * MB);        // 8 MB (bh,s,d)
    unsigned short* Kb  = (unsigned short*)(ws + 26 * MB);        // 8 MB (bh,i,d) compacted
    unsigned short* VtG = (unsigned short*)(ws + 34 * MB);        // 8 MB (bh,d,i) compacted
    // aux region (42MB+): idx/masks — never aliased with anything.
    int*   idx1 = (int*)(ws + 42 * MB);                           // 32 KB
    float* Mf   = (float*)(ws + 42 * MB + 32 * KB);               // 32 KB
    float* Mc   = (float*)(ws + 42 * MB + 64 * KB);               // 32 KB
    int*   nv   = (int*)(ws + 42 * MB + 96 * KB);                 // 16 B
    // ctx reuses the Xbq region (dead after proj_qkv; flash writes it,
    // proj_out reads it — strictly stream-ordered).
    unsigned short* ctx = Xbq;                                    // 8 MB (b*s, h*d)

    pre_all<<<dim3(4353), 256, 0, stream>>>(query, value, amask,
                                            Wq, Wk, Wv, Wo,
                                            Xbq, Xbv, Wtq, Wtk, Wtv, Wto,
                                            idx1, nv, Mf, Mc);
    proj_qkv_mfma<<<dim3(64, 4, 3), 256, 0, stream>>>(Xbq, Xbv, Wtq, Wtk, Wtv,
                                                      bq, bk, bv, idx1, nv,
                                                      Qb, Kb, VtG);
    flash_mfma<<<dim3(512), 256, 0, stream>>>(Qb, Kb, VtG, Mf, Mc, nv, ctx);
    proj_out_mfma<<<dim3(64, 4), 256, 0, stream>>>(ctx, Wto, bo, out);
}

// Round 6
// 182.762 us; speedup vs baseline: 1.5509x; 1.0264x over previous
//
#include <hip/hip_runtime.h>

#define B_ 4
#define S_ 2048
#define D_ 512
#define H_ 8

typedef __attribute__((ext_vector_type(8))) __bf16 bf16x8;
typedef __attribute__((ext_vector_type(4))) float f32x4;

#define NEGBIG  -1.442695040e9f          // -1e9 * log2(e): masks live in exp2 domain
#define QSCALE  0.18033688011112042f     // 0.125 * log2(e) folded into Q

// pack two floats -> two bf16 (RNE-ish, ties-up): 2 adds + 1 v_perm
__device__ __forceinline__ unsigned pack_rn(float a, float b) {
    union { float f; unsigned u; } ua, ub; ua.f = a; ub.f = b;
    return __builtin_amdgcn_perm(ub.u + 0x8000u, ua.u + 0x8000u, 0x07060302u);
}

// async global->LDS, 16B per lane. LDS dest = wave-uniform base + lane*16.
__device__ __forceinline__ void gl16(const void* g, void* l) {
    __builtin_amdgcn_global_load_lds(
        (const __attribute__((address_space(1))) unsigned int*)g,
        (__attribute__((address_space(3))) unsigned int*)l, 16, 0, 0);
}

// ---------------------------------------------------------------------------
// Fused preprocessing (one launch) — UNCHANGED from r5.
//   bid <  4096 : cast_x  — fp32->bf16 cast of query/value activations
//   bid <  4352 : cast_wt — coalesced weight cast+transpose via LDS tile
//   bid == 4352 : compact+mask — prefetched ballot scan + exp2-domain masks.
// ---------------------------------------------------------------------------
__global__ __launch_bounds__(256) void pre_all(
    const float* __restrict__ q, const float* __restrict__ v,
    const int* __restrict__ am,
    const float* __restrict__ Wq, const float* __restrict__ Wk,
    const float* __restrict__ Wv, const float* __restrict__ Wo,
    unsigned short* __restrict__ xq, unsigned short* __restrict__ xv,
    unsigned short* __restrict__ Tq, unsigned short* __restrict__ Tk,
    unsigned short* __restrict__ Tv, unsigned short* __restrict__ To,
    int* __restrict__ idxc, int* __restrict__ nvout,
    float* __restrict__ Mf, float* __restrict__ Mc)
{
    const int bid = blockIdx.x;
    const int tid = threadIdx.x;

    if (bid < 4096) {                       // ---- cast_x ----
        const int z = bid >> 11, xb = bid & 2047;
        const float* src = z ? v : q;
        unsigned short* dst = z ? xv : xq;
        int i = (xb * 256 + tid) * 8;
        float4 f0 = *(const float4*)&src[i];
        float4 f1 = *(const float4*)&src[i + 4];
        uint4 o;
        o.x = pack_rn(f0.x, f0.y); o.y = pack_rn(f0.z, f0.w);
        o.z = pack_rn(f1.x, f1.y); o.w = pack_rn(f1.z, f1.w);
        *(uint4*)&dst[i] = o;
    } else if (bid < 4352) {                // ---- cast_wt ----
        int r = bid - 4096;
        int z = r >> 6, rem = r & 63;
        const float* W = (z == 0) ? Wq : (z == 1) ? Wk : (z == 2) ? Wv : Wo;
        unsigned short* T = (z == 0) ? Tq : (z == 1) ? Tk : (z == 2) ? Tv : To;
        int n0 = (rem & 7) * 64, k0 = (rem >> 3) * 64;

        __shared__ float Ts[64][69];
        #pragma unroll
        for (int it = 0; it < 4; it++) {
            int lin = tid + it * 256;
            int kr = lin >> 4, c4 = (lin & 15) * 4;
            float4 vv = *(const float4*)&W[(k0 + kr) * 512 + n0 + c4];
            Ts[kr][c4 + 0] = vv.x; Ts[kr][c4 + 1] = vv.y;
            Ts[kr][c4 + 2] = vv.z; Ts[kr][c4 + 3] = vv.w;
        }
        __syncthreads();
        int n = tid >> 2, kc = tid & 3;
        unsigned p[8];
        #pragma unroll
        for (int j = 0; j < 8; j++)
            p[j] = pack_rn(Ts[kc * 16 + 2 * j][n], Ts[kc * 16 + 2 * j + 1][n]);
        unsigned short* dst = &T[(n0 + n) * 512 + k0 + kc * 16];
        *(uint4*)dst       = *(uint4*)&p[0];
        *(uint4*)(dst + 8) = *(uint4*)&p[4];
    } else {                                // ---- compact + masks ----
        const int w = tid >> 6, lane = tid & 63;   // wave w = batch w
        const int* amb = am + w * 2048;
        int m[32];
        #pragma unroll
        for (int s = 0; s < 32; s++) m[s] = amb[s * 64 + lane];  // all issued up front

        int* ib = idxc + w * 2048;
        const unsigned long long lt = (1ULL << lane) - 1ULL;
        int base = 0;
        #pragma unroll
        for (int s = 0; s < 32; s++) {
            unsigned long long bal = __ballot(m[s] != 0);
            if (m[s]) ib[base + __popcll(bal & lt)] = s * 64 + lane;
            base += __popcll(bal);
        }
        const int nv = base;
        for (int i = nv + lane; i < 2048; i += 64) ib[i] = 0;   // pad -> row 0
        float* mfb = Mf + w * 2048;
        float* mcb = Mc + w * 2048;
        #pragma unroll
        for (int s = 0; s < 32; s++) {
            int i = s * 64 + lane;
            mfb[i] = m[s] ? 0.f : NEGBIG;
            mcb[i] = (i < nv) ? 0.f : NEGBIG;
        }
        if (lane == 0) nvout[w] = nv;
    }
}

// ---------------------------------------------------------------------------
// QKV projection GEMM, 128m x 64n tiles, DOUBLE-BUFFERED gl16 staging with
// counted vmcnt (T3/T4 minimum): STAGE(nxt) -> vmcnt(6) -> barrier ->
// compute(cur) -> barrier. The 6 next-tile loads stay in flight under the
// current tile's MFMAs — never drained to 0 in the loop.
// Tiles halved in n (vs r5's 128x128) => ~4 blocks/CU for latency overlap.
// Same XOR-chunk swizzle (source-side) + gather + bit-exact epilogues as r5.
// z=0 (Q): m=feature, n=s (full)      -> (bh,s,d), scaled
// z=1 (K): m=feature, n=compacted s   -> (bh,i,d)
// z=2 (V): m=compacted s, n=feature   -> (bh,d,i)
// ---------------------------------------------------------------------------
__global__ __launch_bounds__(256) void proj_qkv_mfma(
    const unsigned short* __restrict__ Xq, const unsigned short* __restrict__ Xv,
    const unsigned short* __restrict__ Wtq, const unsigned short* __restrict__ Wtk,
    const unsigned short* __restrict__ Wtv,
    const float* __restrict__ bq, const float* __restrict__ bk,
    const float* __restrict__ bv,
    const int* __restrict__ idxc, const int* __restrict__ nv1,
    unsigned short* __restrict__ Qb, unsigned short* __restrict__ Kb,
    unsigned short* __restrict__ VtG)
{
    const int z = blockIdx.z;
    const unsigned short* A  = (z == 0) ? Wtq : (z == 1) ? Wtk : Xv;
    const unsigned short* Bm = (z == 0) ? Xq  : (z == 1) ? Xv  : Wtv;
    const float* bias        = (z == 0) ? bq  : (z == 1) ? bk  : bv;
    const int lin0 = blockIdx.y * 128 + blockIdx.x;       // 0..511
    const int m0 = (z < 2) ? blockIdx.y * 128 : (lin0 >> 3) * 128;
    const int n0 = (z < 2) ? blockIdx.x * 64  : (lin0 & 7) * 64;

    // early-exit for blocks entirely in the dead compacted region
    if (z == 1) {
        int bb = n0 >> 11, cap = (nv1[bb] + 63) & ~63;
        if (cap < 64) cap = 64;
        if ((n0 & 2047) >= cap) return;
    }
    if (z == 2) {
        int bb = m0 >> 11, cap = (nv1[bb] + 63) & ~63;
        if (cap < 64) cap = 64;
        if ((m0 & 2047) >= cap) return;
    }

    const int tid = threadIdx.x;
    const int w = tid >> 6, lane = tid & 63;
    const int l15 = lane & 15, quad = lane >> 4;
    const int wm = (w >> 1) * 64, wn = (w & 1) * 32;

    __shared__ unsigned short As[2][128 * 64];
    __shared__ unsigned short Bs[2][64 * 64];

    // staging: srw = tid>>3 covers rows {is*32+srw}; source chunk pre-swizzled.
    const int srw  = tid >> 3;                       // 0..31
    const int csrc = (tid & 7) ^ (srw & 7);
    const unsigned short* aS[4];
    const unsigned short* bS[2];
    #pragma unroll
    for (int is = 0; is < 4; is++) {
        int ra = m0 + is * 32 + srw;
        long sa = ra;
        if (z == 2) { int bb = ra >> 11; sa = (long)bb * 2048 + idxc[bb * 2048 + (ra & 2047)]; }
        aS[is] = A + sa * 512 + csrc * 8;
    }
    #pragma unroll
    for (int is = 0; is < 2; is++) {
        int rb = n0 + is * 32 + srw;
        long sb = rb;
        if (z == 1) { int bb = rb >> 11; sb = (long)bb * 2048 + idxc[bb * 2048 + (rb & 2047)]; }
        bS[is] = Bm + sb * 512 + csrc * 8;
    }

    const int koff0 = ((quad    ) ^ (l15 & 7)) * 8;  // undo swizzle on read
    const int koff1 = ((quad + 4) ^ (l15 & 7)) * 8;

    f32x4 acc[4][2];
    #pragma unroll
    for (int i = 0; i < 4; i++)
        #pragma unroll
        for (int j = 0; j < 2; j++) acc[i][j] = (f32x4){0.f, 0.f, 0.f, 0.f};

    // ---- double-buffered K loop: 8 chunks of 64 ----
    #define STAGE_Q(buf, k0)                                        \
        do {                                                        \
            _Pragma("unroll")                                       \
            for (int is = 0; is < 4; is++)                          \
                gl16(aS[is] + (k0), &As[buf][is * 2048 + w * 512]); \
            _Pragma("unroll")                                       \
            for (int is = 0; is < 2; is++)                          \
                gl16(bS[is] + (k0), &Bs[buf][is * 2048 + w * 512]); \
        } while (0)

    STAGE_Q(0, 0);
    for (int k = 0; k < 8; k++) {
        const int cur = k & 1;
        if (k < 7) {
            STAGE_Q(cur ^ 1, (k + 1) * 64);
            asm volatile("s_waitcnt vmcnt(6)" ::: "memory");
        } else {
            asm volatile("s_waitcnt vmcnt(0)" ::: "memory");
        }
        asm volatile("s_barrier" ::: "memory");
        #pragma unroll
        for (int kc = 0; kc < 2; kc++) {
            const int ko = kc ? koff1 : koff0;
            bf16x8 a[4], bb[2];
            #pragma unroll
            for (int i = 0; i < 4; i++)
                a[i] = *(const bf16x8*)&As[cur][(wm + 16 * i + l15) * 64 + ko];
            #pragma unroll
            for (int j = 0; j < 2; j++)
                bb[j] = *(const bf16x8*)&Bs[cur][(wn + 16 * j + l15) * 64 + ko];
            #pragma unroll
            for (int i = 0; i < 4; i++)
                #pragma unroll
                for (int j = 0; j < 2; j++)
                    acc[i][j] = __builtin_amdgcn_mfma_f32_16x16x32_bf16(a[i], bb[j], acc[i][j], 0, 0, 0);
        }
        asm volatile("s_barrier" ::: "memory");
    }
    #undef STAGE_Q

    if (z == 2) {
        // V: cols = feature, rows = compacted s. ushort4 along s into (bh,d,i).
        #pragma unroll
        for (int j = 0; j < 2; j++) {
            int N = n0 + wn + 16 * j + l15;
            float bv_ = bias[N];
            int h = N >> 6, d = N & 63;
            #pragma unroll
            for (int i = 0; i < 4; i++) {
                int Mb = m0 + wm + 16 * i + quad * 4;
                int b = Mb >> 11, s = Mb & 2047;
                uint2 o;
                o.x = pack_rn(acc[i][j][0] + bv_, acc[i][j][1] + bv_);
                o.y = pack_rn(acc[i][j][2] + bv_, acc[i][j][3] + bv_);
                *(uint2*)&VtG[((b * H_ + h) * 64 + d) * 2048 + s] = o;
            }
        }
    } else {
        // Q/K: cols = s (K: compacted), rows = feature. ushort4 along d.
        unsigned short* dst = (z == 0) ? Qb : Kb;
        const float scale = (z == 0) ? QSCALE : 1.0f;
        #pragma unroll
        for (int j = 0; j < 2; j++) {
            int sg = n0 + wn + 16 * j + l15;
            int b = sg >> 11, s = sg & 2047;
            #pragma unroll
            for (int i = 0; i < 4; i++) {
                int F = m0 + wm + 16 * i + quad * 4;
                int h = F >> 6, d = F & 63;
                float4 b4 = *(const float4*)&bias[F];
                uint2 o;
                o.x = pack_rn((acc[i][j][0] + b4.x) * scale, (acc[i][j][1] + b4.y) * scale);
                o.y = pack_rn((acc[i][j][2] + b4.z) * scale, (acc[i][j][3] + b4.w) * scale);
                *(uint2*)&dst[((b * H_ + h) * 2048 + s) * 64 + d] = o;
            }
        }
    }
}

// ---------------------------------------------------------------------------
// MFMA flash attention over COMPACTED keys — byte-identical to the verified
// r4/r5 kernel (compaction + XOR-swizzled LDS + XCD swizzle + defer-max +
// setprio).
// ---------------------------------------------------------------------------
__global__ __launch_bounds__(256, 2) void flash_mfma(
    const unsigned short* __restrict__ Qg, const unsigned short* __restrict__ Kg,
    const unsigned short* __restrict__ VtG, const float* __restrict__ Mf,
    const float* __restrict__ Mc, const int* __restrict__ nvalid,
    unsigned short* __restrict__ ctxB)
{
    const int bid = blockIdx.x;                  // 0..511
    const int xcd = bid & 7, idx = bid >> 3;     // XCD x owns bh 4x..4x+3
    const int bh = xcd * 4 + (idx & 3);
    const int q0 = (idx >> 2) * 128;
    const int b = bh >> 3, h = bh & 7;

    const int tid = threadIdx.x;
    const int w = tid >> 6, lane = tid & 63;
    const int l15 = lane & 15, quad = lane >> 4;
    const int swz = l15 & 7;

    __shared__ unsigned short Ks[2][64 * 64];    // pad-free, XOR-chunk-swizzled
    __shared__ unsigned short Ps[4][32 * 64];    // per-wave P, same swizzle
    unsigned short* pw = &Ps[w][0];

    const int nv = nvalid[b];
    int ntiles = (nv + 63) >> 6;
    if (ntiles < 1) ntiles = 1;

    const float* mfb = Mf + b * 2048;
    const float* mcp = Mc + b * 2048 + quad * 4;

    // Q fragments (B-operand) + query mask, resident
    bf16x8 qf[2][2];
    float mq[2];
    #pragma unroll
    for (int qb = 0; qb < 2; qb++) {
        int qrow = q0 + w * 32 + qb * 16 + l15;
        const unsigned short* p = &Qg[((long)bh * 2048 + qrow) * 64 + quad * 8];
        qf[qb][0] = *(const bf16x8*)p;
        qf[qb][1] = *(const bf16x8*)(p + 32);
        mq[qb] = mfb[qrow];
    }

    // V row pointers (bh,d,i layout)
    const unsigned short* vp[4];
    #pragma unroll
    for (int i = 0; i < 4; i++)
        vp[i] = VtG + ((long)bh * 64 + i * 16 + l15) * 2048 + quad * 8;

    // K staging: thread -> (row = tid>>2, chunks (tid&3)*2, +1) of 64x64 tile
    const int srow = tid >> 2;
    const int sch  = (tid & 3) * 2;
    const unsigned short* kgb = Kg + (long)bh * 2048 * 64;
    const int sw0 = srow * 64 + ((sch    ) ^ (srow & 7)) * 8;
    const int sw1 = srow * 64 + ((sch + 1) ^ (srow & 7)) * 8;

    // preamble: stage tile 0 into Ks[0]
    {
        uint4 a = *(const uint4*)&kgb[srow * 64 + sch * 8];
        uint4 c = *(const uint4*)&kgb[srow * 64 + sch * 8 + 8];
        *(uint4*)&Ks[0][sw0] = a;
        *(uint4*)&Ks[0][sw1] = c;
    }

    // swizzled fragment-read chunk offsets (kc=0 -> chunk quad, kc=1 -> 4+quad)
    const int koff0 = ((quad    ) ^ swz) * 8;
    const int koff1 = ((quad + 4) ^ swz) * 8;

    f32x4 accO[2][4];
    #pragma unroll
    for (int qb = 0; qb < 2; qb++)
        #pragma unroll
        for (int dt = 0; dt < 4; dt++) accO[qb][dt] = (f32x4){0.f, 0.f, 0.f, 0.f};
    float mi[2] = {-3.0e38f, -3.0e38f};
    float li[2] = {0.f, 0.f};

    __syncthreads();

    for (int t = 0; t < ntiles; t++) {
        const int kt = t * 64;
        const int ktn = (t + 1 < ntiles) ? kt + 64 : kt;
        const int cur = t & 1, nxt = cur ^ 1;

        // [A] issue global loads: V frags + key-mask for THIS tile, K for NEXT
        bf16x8 vf[4][2];
        #pragma unroll
        for (int dt = 0; dt < 4; dt++) {
            vf[dt][0] = *(const bf16x8*)(vp[dt] + kt);
            vf[dt][1] = *(const bf16x8*)(vp[dt] + kt + 32);
        }
        uint4 kst0 = *(const uint4*)&kgb[(ktn + srow) * 64 + sch * 8];
        uint4 kst1 = *(const uint4*)&kgb[(ktn + srow) * 64 + sch * 8 + 8];
        f32x4 kmf[4];
        #pragma unroll
        for (int nt = 0; nt < 4; nt++)
            kmf[nt] = *(const f32x4*)(mcp + kt + nt * 16);

        // [C] K frags from LDS buf[cur] (swizzled); QK: S^T (rows=key, cols=q)
        bf16x8 kf[4][2];
        #pragma unroll
        for (int nt = 0; nt < 4; nt++) {
            kf[nt][0] = *(const bf16x8*)&Ks[cur][(nt * 16 + l15) * 64 + koff0];
            kf[nt][1] = *(const bf16x8*)&Ks[cur][(nt * 16 + l15) * 64 + koff1];
        }
        f32x4 sc[2][4];
        #pragma unroll
        for (int qb = 0; qb < 2; qb++)
            #pragma unroll
            for (int nt = 0; nt < 4; nt++) {
                f32x4 c = kmf[nt];               // masks as C-init: exact
                c[0] += mq[qb]; c[1] += mq[qb]; c[2] += mq[qb]; c[3] += mq[qb];
                sc[qb][nt] = c;
            }
        __builtin_amdgcn_s_setprio(1);
        #pragma unroll
        for (int qb = 0; qb < 2; qb++)
            #pragma unroll
            for (int nt = 0; nt < 4; nt++) {
                sc[qb][nt] = __builtin_amdgcn_mfma_f32_16x16x32_bf16(
                    kf[nt][0], qf[qb][0], sc[qb][nt], 0, 0, 0);
                sc[qb][nt] = __builtin_amdgcn_mfma_f32_16x16x32_bf16(
                    kf[nt][1], qf[qb][1], sc[qb][nt], 0, 0, 0);
            }
        __builtin_amdgcn_s_setprio(0);

        // [D] online softmax (reduce over keys = in-lane + quad shfls)
        #pragma unroll
        for (int qb = 0; qb < 2; qb++) {
            float mloc = fmaxf(fmaxf(sc[qb][0][0], sc[qb][0][1]),
                               fmaxf(sc[qb][0][2], sc[qb][0][3]));
            #pragma unroll
            for (int nt = 1; nt < 4; nt++)
                mloc = fmaxf(mloc, fmaxf(fmaxf(sc[qb][nt][0], sc[qb][nt][1]),
                                         fmaxf(sc[qb][nt][2], sc[qb][nt][3])));
            mloc = fmaxf(mloc, __shfl_xor(mloc, 16));
            mloc = fmaxf(mloc, __shfl_xor(mloc, 32));

            float mn = mi[qb];
            if (!__all(mloc <= mn + 4.f)) {      // defer-max: P bounded by 2^4
                float mo = mn;
                mn = fmaxf(mo, mloc);
                float alpha = __builtin_amdgcn_exp2f(mo - mn);
                li[qb] *= alpha;
                #pragma unroll
                for (int dt = 0; dt < 4; dt++) {
                    accO[qb][dt][0] *= alpha; accO[qb][dt][1] *= alpha;
                    accO[qb][dt][2] *= alpha; accO[qb][dt][3] *= alpha;
                }
                mi[qb] = mn;
            }

            float ps = 0.f;
            const int prbase = (qb * 16 + l15) * 64;
            #pragma unroll
            for (int nt = 0; nt < 4; nt++) {
                float p0 = __builtin_amdgcn_exp2f(sc[qb][nt][0] - mn);
                float p1 = __builtin_amdgcn_exp2f(sc[qb][nt][1] - mn);
                float p2 = __builtin_amdgcn_exp2f(sc[qb][nt][2] - mn);
                float p3 = __builtin_amdgcn_exp2f(sc[qb][nt][3] - mn);
                ps += (p0 + p1) + (p2 + p3);
                // keys nt*16+quad*4..+3 -> chunk 2nt+(quad>>1), sub (quad&1)*4
                uint2 pp;
                pp.x = pack_rn(p0, p1);
                pp.y = pack_rn(p2, p3);
                *(uint2*)&pw[prbase + ((2 * nt + (quad >> 1)) ^ swz) * 8 + (quad & 1) * 4] = pp;
            }
            ps += __shfl_xor(ps, 16);
            ps += __shfl_xor(ps, 32);
            li[qb] += ps;
        }

        // [E] PV: O^T += Vt (A) x P^T (B)
        #pragma unroll
        for (int qb = 0; qb < 2; qb++) {
            bf16x8 pf0 = *(const bf16x8*)&pw[(qb * 16 + l15) * 64 + koff0];
            bf16x8 pf1 = *(const bf16x8*)&pw[(qb * 16 + l15) * 64 + koff1];
            __builtin_amdgcn_s_setprio(1);
            #pragma unroll
            for (int dt = 0; dt < 4; dt++) {
                accO[qb][dt] = __builtin_amdgcn_mfma_f32_16x16x32_bf16(
                    vf[dt][0], pf0, accO[qb][dt], 0, 0, 0);
                accO[qb][dt] = __builtin_amdgcn_mfma_f32_16x16x32_bf16(
                    vf[dt][1], pf1, accO[qb][dt], 0, 0, 0);
            }
            __builtin_amdgcn_s_setprio(0);
        }

        // [F] commit next K tile to LDS (waits the [A] loads), [G] barrier
        *(uint4*)&Ks[nxt][sw0] = kst0;
        *(uint4*)&Ks[nxt][sw1] = kst1;
        __syncthreads();
    }

    #pragma unroll
    for (int qb = 0; qb < 2; qb++) {
        float inv = 1.f / li[qb];
        int q = q0 + w * 32 + qb * 16 + l15;
        int obase = (b * 2048 + q) * 512 + h * 64 + quad * 4;
        #pragma unroll
        for (int dt = 0; dt < 4; dt++) {
            uint2 o;
            o.x = pack_rn(accO[qb][dt][0] * inv, accO[qb][dt][1] * inv);
            o.y = pack_rn(accO[qb][dt][2] * inv, accO[qb][dt][3] * inv);
            *(uint2*)&ctxB[obase + dt * 16] = o;
        }
    }
}

// ---------------------------------------------------------------------------
// Output projection: out(fp32) = ctx_bf16 @ Wo + bo.
// 128m x 64n tiles (512 blocks = 2/CU, was 1/CU), double-buffered gl16
// staging with counted vmcnt — same schedule as proj_qkv.
// ---------------------------------------------------------------------------
__global__ __launch_bounds__(256) void proj_out_mfma(
    const unsigned short* __restrict__ ctxB, const unsigned short* __restrict__ Wto,
    const float* __restrict__ bo, float* __restrict__ out)
{
    const int m0 = blockIdx.y * 128, n0 = blockIdx.x * 64;
    const int tid = threadIdx.x;
    const int w = tid >> 6, lane = tid & 63;
    const int l15 = lane & 15, quad = lane >> 4;
    const int wm = (w >> 1) * 64, wn = (w & 1) * 32;

    __shared__ unsigned short As[2][128 * 64];
    __shared__ unsigned short Bs[2][64 * 64];

    const int srw  = tid >> 3;
    const int csrc = (tid & 7) ^ (srw & 7);
    const unsigned short* aS[4];
    const unsigned short* bS[2];
    #pragma unroll
    for (int is = 0; is < 4; is++)
        aS[is] = Wto  + (long)(m0 + is * 32 + srw) * 512 + csrc * 8;
    #pragma unroll
    for (int is = 0; is < 2; is++)
        bS[is] = ctxB + (long)(n0 + is * 32 + srw) * 512 + csrc * 8;

    const int koff0 = ((quad    ) ^ (l15 & 7)) * 8;
    const int koff1 = ((quad + 4) ^ (l15 & 7)) * 8;

    f32x4 acc[4][2];
    #pragma unroll
    for (int i = 0; i < 4; i++)
        #pragma unroll
        for (int j = 0; j < 2; j++) acc[i][j] = (f32x4){0.f, 0.f, 0.f, 0.f};

    #define STAGE_O(buf, k0)                                        \
        do {                                                        \
            _Pragma("unroll")                                       \
            for (int is = 0; is < 4; is++)                          \
                gl16(aS[is] + (k0), &As[buf][is * 2048 + w * 512]); \
            _Pragma("unroll")                                       \
            for (int is = 0; is < 2; is++)                          \
                gl16(bS[is] + (k0), &Bs[buf][is * 2048 + w * 512]); \
        } while (0)

    STAGE_O(0, 0);
    for (int k = 0; k < 8; k++) {
        const int cur = k & 1;
        if (k < 7) {
            STAGE_O(cur ^ 1, (k + 1) * 64);
            asm volatile("s_waitcnt vmcnt(6)" ::: "memory");
        } else {
            asm volatile("s_waitcnt vmcnt(0)" ::: "memory");
        }
        asm volatile("s_barrier" ::: "memory");
        #pragma unroll
        for (int kc = 0; kc < 2; kc++) {
            const int ko = kc ? koff1 : koff0;
            bf16x8 a[4], bb[2];
            #pragma unroll
            for (int i = 0; i < 4; i++)
                a[i] = *(const bf16x8*)&As[cur][(wm + 16 * i + l15) * 64 + ko];
            #pragma unroll
            for (int j = 0; j < 2; j++)
                bb[j] = *(const bf16x8*)&Bs[cur][(wn + 16 * j + l15) * 64 + ko];
            #pragma unroll
            for (int i = 0; i < 4; i++)
                #pragma unroll
                for (int j = 0; j < 2; j++)
                    acc[i][j] = __builtin_amdgcn_mfma_f32_16x16x32_bf16(a[i], bb[j], acc[i][j], 0, 0, 0);
        }
        asm volatile("s_barrier" ::: "memory");
    }
    #undef STAGE_O

    #pragma unroll
    for (int j = 0; j < 2; j++) {
        int sg = n0 + wn + 16 * j + l15;
        #pragma unroll
        for (int i = 0; i < 4; i++) {
            int F = m0 + wm + 16 * i + quad * 4;
            float4 b4 = *(const float4*)&bo[F];
            float4 vv;
            vv.x = acc[i][j][0] + b4.x;
            vv.y = acc[i][j][1] + b4.y;
            vv.z = acc[i][j][2] + b4.z;
            vv.w = acc[i][j][3] + b4.w;
            *(float4*)&out[sg * 512 + F] = vv;
        }
    }
}

extern "C" void kernel_launch(void* const* d_in, const int* in_sizes, int n_in,
                              void* d_out, int out_size, void* d_ws, size_t ws_size,
                              hipStream_t stream)
{
    const float* query = (const float*)d_in[0];
    const float* value = (const float*)d_in[1];
    const int*   amask = (const int*)d_in[2];
    const float* Wq = (const float*)d_in[3];
    const float* bq = (const float*)d_in[4];
    const float* Wk = (const float*)d_in[5];
    const float* bk = (const float*)d_in[6];
    const float* Wv = (const float*)d_in[7];
    const float* bv = (const float*)d_in[8];
    const float* Wo = (const float*)d_in[9];
    const float* bo = (const float*)d_in[10];
    float* out = (float*)d_out;

    char* ws = (char*)d_ws;
    const size_t MB = 1 << 20;
    const size_t KB = 1 << 10;
    unsigned short* Xbq = (unsigned short*)(ws);                  // 8 MB bf16
    unsigned short* Xbv = (unsigned short*)(ws + 8 * MB);         // 8 MB
    unsigned short* Wtq = (unsigned short*)(ws + 16 * MB);        // 0.5 MB each
    unsigned short* Wtk = (unsigned short*)(ws + 16 * MB + MB / 2);
    unsigned short* Wtv = (unsigned short*)(ws + 17 * MB);
    unsigned short* Wto = (unsigned short*)(ws + 17 * MB + MB / 2);
    unsigned short* Qb  = (unsigned short*)(ws + 18 * MB);        // 8 MB (bh,s,d)
    unsigned short* Kb  = (unsigned short*)(ws + 26 * MB);        // 8 MB (bh,i,d) compacted
    unsigned short* VtG = (unsigned short*)(ws + 34 * MB);        // 8 MB (bh,d,i) compacted
    // aux region (42MB+): idx/masks — never aliased with anything.
    int*   idx1 = (int*)(ws + 42 * MB);                           // 32 KB
    float* Mf   = (float*)(ws + 42 * MB + 32 * KB);               // 32 KB
    float* Mc   = (float*)(ws + 42 * MB + 64 * KB);               // 32 KB
    int*   nv   = (int*)(ws + 42 * MB + 96 * KB);                 // 16 B
    // ctx reuses the Xbq region (dead after proj_qkv; flash writes it,
    // proj_out reads it — strictly stream-ordered).
    unsigned short* ctx = Xbq;                                    // 8 MB (b*s, h*d)

    pre_all<<<dim3(4353), 256, 0, stream>>>(query, value, amask,
                                            Wq, Wk, Wv, Wo,
                                            Xbq, Xbv, Wtq, Wtk, Wtv, Wto,
                                            idx1, nv, Mf, Mc);
    proj_qkv_mfma<<<dim3(128, 4, 3), 256, 0, stream>>>(Xbq, Xbv, Wtq, Wtk, Wtv,
                                                       bq, bk, bv, idx1, nv,
                                                       Qb, Kb, VtG);
    flash_mfma<<<dim3(512), 256, 0, stream>>>(Qb, Kb, VtG, Mf, Mc, nv, ctx);
    proj_out_mfma<<<dim3(128, 4), 256, 0, stream>>>(ctx, Wto, bo, out);
}